// Round 7
// baseline (323.052 us; speedup 1.0000x reference)
//
#include <hip/hip_runtime.h>
#include <math.h>

// ---------------------------------------------------------------------------
// RTF-SSM block, MI355X. FFT path replaced by:
//   K = impulse response of B(z)/A(z), truncated at 512 taps (Newton
//   power-series inversion, 9 wave-parallel doubling steps).
//   causal conv = Toeplitz-block bf16 MFMA (16x16x32), A-frags prebuilt.
//   GEMMs (65536x256x256) bf16 MFMA with fused bias/gelu/skip/LN/max.
// R6: VALU diet in k_conv (gelu via exp2+rcp, sliding swizzled LDS addrs).
// R9: kgen structural fix (8 waves/block co-residency) fused into k_pzk.
// R10: conv 8ch x 1024t blocks (16B-granular y1 stores).
// R11 FAILED: gemm2+gemm3 fused while xeT aliased d_out -> cross-block race
//   (phase-2 yout fp32 writes clobber xeT bytes other blocks' phase-1 still
//   reads as xe skip; fp32 bits as bf16 -> NaN). Math was verified correct.
// R12: race fixed by PLACEMENT, selected at runtime on ws_size:
//   - ws_size >= 74,203,136: xeT lives in ws -> fused k_g23 is race-free
//     (reads ws only, writes yout/maxy only).
//   - else: xeT in d_out -> known-passing split k_gemm2 + k_gemm3 (R10).
//   Kernel names differ per path so rocprof reveals which executed.
// ---------------------------------------------------------------------------

#define BSZ   8
#define SEQ   8192
#define CHN   256
#define ORD   64
#define STAPS 512
#define NDD   17            // d-pairs: covers d = 0..33 (taps to 543 >= 511)
#define PREPAD 544          // history prepad (>= 528 needed), 16-aligned
#define XROW  (PREPAD + SEQ) // 8736 elems per (b,c) row of xe^T
#define MTOT  (BSZ * SEQ)   // 65536
#define YELEMS (MTOT * CHN) // 16777216

#define CT2   1024          // conv t-tile per block
#define CTP   1032          // conv bnc row stride (8-short pad)
#define CROW2 2048          // conv xet row elems (4 x 512 staged)

typedef short s16x8 __attribute__((ext_vector_type(8)));
typedef float f32x4 __attribute__((ext_vector_type(4)));

#define MFMA16(a, b, c) __builtin_amdgcn_mfma_f32_16x16x32_bf16((a), (b), (c), 0, 0, 0)

// async global->LDS 16B: LDS dest = wave-uniform base + lane*16
__device__ __forceinline__ void gll16(const void* g, void* l) {
  __builtin_amdgcn_global_load_lds(
      (const __attribute__((address_space(1))) unsigned int*)g,
      (__attribute__((address_space(3))) unsigned int*)l, 16, 0, 0);
}

// XOR-perm chunk layout: chunk p of (row,h) stored at elems PERMC
#define PERMC(row, h) (((row) * 8 + ((h) ^ ((row) & 7))) * 8)

__device__ __forceinline__ unsigned short f2bf(float f) {
  unsigned u = __float_as_uint(f);
  return (unsigned short)((u + 0x7FFFu + ((u >> 16) & 1u)) >> 16);
}
__device__ __forceinline__ float bf2f(unsigned short h) {
  return __uint_as_float(((unsigned)h) << 16);
}
// tanh-form gelu: x * sigmoid(2*sqrt(2/pi)*(x + 0.044715 x^3)).
// |err| vs exact erf-gelu < ~2e-4, << bf16 noise.
__device__ __forceinline__ float geluf(float x) {
  float x2 = x * x;
  float y = x * __builtin_fmaf(0.0356774081f, x2, 0.7978845608f);
  float e = __builtin_amdgcn_exp2f(-2.8853900818f * y);  // exp(-2y)
  return x * __builtin_amdgcn_rcpf(1.0f + e);
}
__device__ __forceinline__ uint4 packbf8(float4 a, float4 b) {
  uint4 r;
  r.x = (unsigned)f2bf(a.x) | ((unsigned)f2bf(a.y) << 16);
  r.y = (unsigned)f2bf(a.z) | ((unsigned)f2bf(a.w) << 16);
  r.z = (unsigned)f2bf(b.x) | ((unsigned)f2bf(b.y) << 16);
  r.w = (unsigned)f2bf(b.z) | ((unsigned)f2bf(b.w) << 16);
  return r;
}

// ---------------- K-gen: Newton inversion of A(z), one wave per channel.
__device__ __forceinline__ void kgen8(float* smemk, const float* A, const float* Bp,
                                      unsigned short* afr, int blk) {
  int tid = threadIdx.x, lane = tid & 63, wv = tid >> 6;
  int c = blk * 8 + wv;
  float* base = smemk + wv * 1872;            // 8 waves x 7488B = 59904B
  float* G0 = base;                           // [584], G0[64+t] = G[t]
  float* G1 = base + 584;                     // [584], G1[65+t] = G[t]
  float* Et = base + 1168;                    // [64]
  float* Asl = base + 1232;                   // [64]
  float* Bsl = base + 1296;                   // [64]
  float* Kb = base + 1360;                    // [512]

  Asl[lane] = A[(size_t)c * ORD + lane];      // a[u] = Asl[u-1], u in [1,64]
  Bsl[lane] = Bp[(size_t)c * ORD + lane];
  for (int i = lane; i < 1168; i += 64) base[i] = 0.f;  // zero both G copies
  if (lane == 0) { G0[64] = 1.f; G1[65] = 1.f; }        // G[0] = 1

  for (int n = 1; n < STAPS; n <<= 1) {
    int par = (n + lane) & 1;
    const float* Gc = par ? G1 : G0;
    int I0 = 64 + n + lane + par;             // even
    float e0 = 0.f, e1 = 0.f, e2 = 0.f, e3 = 0.f;
#pragma unroll
    for (int g = 0; g < 16; ++g) {
      float4 av = *(const float4*)&Asl[4 * g];
      float2 vA = *(const float2*)&Gc[I0 - 4 * g - 2];
      float2 vB = *(const float2*)&Gc[I0 - 4 * g - 4];
      e0 += av.x * vA.y;                      // u = 4g+1
      e1 += av.y * vA.x;                      // u = 4g+2
      e2 += av.z * vB.y;                      // u = 4g+3
      e3 += av.w * vB.x;                      // u = 4g+4
    }
    Et[lane] = (e0 + e1) + (e2 + e3);
    int nk = (n + 63) >> 6;
    for (int k = 0; k < nk; ++k) {
      int idx = k * 64 + lane;
      int parU = (idx + 1) & 1;
      const float* Gu = parU ? G1 : G0;
      int J0 = 64 + idx - 1 + parU;           // even
      float a0 = 0.f, a1 = 0.f, a2 = 0.f, a3 = 0.f;
#pragma unroll
      for (int g = 0; g < 16; ++g) {
        float4 ev = *(const float4*)&Et[4 * g];
        float2 vA = *(const float2*)&Gu[J0 - 4 * g];
        float2 vB = *(const float2*)&Gu[J0 - 4 * g - 2];
        a0 += ev.x * vA.y;                    // i = 4g
        a1 += ev.y * vA.x;                    // i = 4g+1
        a2 += ev.z * vB.y;                    // i = 4g+2
        a3 += ev.w * vB.x;                    // i = 4g+3
      }
      if (idx < n) {
        float gv = -((a0 + a1) + (a2 + a3));
        G0[64 + n + idx] = gv;
        G1[65 + n + idx] = gv;
      }
    }
  }

  for (int k = 0; k < 8; ++k) {
    int t = k * 64 + lane;
    int parB = (t + 1) & 1;
    const float* Gb = parB ? G1 : G0;
    int J0 = 64 + t - 1 + parB;               // even
    float a0 = 0.f, a1 = 0.f, a2 = 0.f, a3 = 0.f;
#pragma unroll
    for (int g = 0; g < 16; ++g) {
      float4 bv = *(const float4*)&Bsl[4 * g];
      float2 vA = *(const float2*)&Gb[J0 - 4 * g];
      float2 vB = *(const float2*)&Gb[J0 - 4 * g - 2];
      a0 += bv.x * vA.y;                      // j = 4g
      a1 += bv.y * vA.x;                      // j = 4g+1
      a2 += bv.z * vB.y;                      // j = 4g+2
      a3 += bv.w * vB.x;                      // j = 4g+3
    }
    Kb[t] = (a0 + a1) + (a2 + a3);
  }

  int m = lane & 15, quad = lane >> 4;
  for (int dd = 0; dd < NDD; ++dd) {
    unsigned short v[8];
#pragma unroll
    for (int j = 0; j < 8; ++j) {
      int k = quad * 8 + j;
      int d = 2 * dd + (k >> 4);
      int p = k & 15;
      int s = 16 * d + m - p;
      float kv = (s >= 0 && s < STAPS) ? Kb[s] : 0.f;
      v[j] = f2bf(kv);
    }
    uint4 pk;
    pk.x = (unsigned)v[0] | ((unsigned)v[1] << 16);
    pk.y = (unsigned)v[2] | ((unsigned)v[3] << 16);
    pk.z = (unsigned)v[4] | ((unsigned)v[5] << 16);
    pk.w = (unsigned)v[6] | ((unsigned)v[7] << 16);
    *(uint4*)(afr + ((size_t)(c * NDD + dd) * 64 + lane) * 8) = pk;
  }
}

// ---------- fused: kgen (blocks [0,32)) + weights->bf16 + zero prepads
__global__ __launch_bounds__(512) void k_pzk(const float* A, const float* Bp,
                                             unsigned short* afr,
                                             const float* we, const float* wf,
                                             const float* wd, unsigned short* owe,
                                             unsigned short* owf, unsigned short* owd,
                                             unsigned short* xeT, uint4* maxbufs) {
  __shared__ __align__(16) float smemk[8 * 1872];   // 59904B (kgen blocks only)
  int bx = blockIdx.x, tid = threadIdx.x;           // grid 690 = 32 kgen + 658 pz
  if (bx < 32) {
    kgen8(smemk, A, Bp, afr, bx);
    return;
  }
  int i = (bx - 32) * 512 + tid;                    // [0, 336896)
  if (i < 196608) {                                 // weights -> bf16
    int which = i >> 16, off = i & 65535;
    if (which == 0)      owe[off] = f2bf(we[off]);
    else if (which == 1) owf[off] = f2bf(wf[off]);
    else                 owd[off] = f2bf(wd[off]);
  } else {
    int j = i - 196608;
    uint4 z; z.x = 0; z.y = 0; z.z = 0; z.w = 0;
    if (j < 139264) {                               // 2048 rows x 68 chunks
      int row = j / 68, cc = j % 68;
      *(uint4*)((char*)xeT + (size_t)row * (XROW * 2) + (size_t)cc * 16) = z;
    } else {
      maxbufs[j - 139264] = z;                      // maxxe (8KB) + maxy (8KB)
    }
  }
}

// --------------- GEMM1 (transposed out): xe^T[cout][t] = W_enc x^T + b_enc
__global__ __launch_bounds__(256) void k_gemm1(const float* x, const unsigned short* wb,
                                               const float* benc, unsigned short* xeT,
                                               unsigned int* maxxe) {
  __shared__ __align__(16) unsigned short As[256 * 64]; // W tile, perm layout
  __shared__ __align__(16) unsigned short Bs[64 * 64];  // x tile, perm layout
  int tid = threadIdx.x, lane = tid & 63, wv = tid >> 6;
  int ln15 = lane & 15, hf = lane >> 4;
  size_t t0 = (size_t)blockIdx.x * 64;          // grid 1024
  int b = (int)(t0 >> 13), tin = (int)(t0 & 8191);
  f32x4 acc[4][4];
#pragma unroll
  for (int i = 0; i < 4; ++i)
#pragma unroll
    for (int j = 0; j < 4; ++j) { acc[i][j][0]=0.f; acc[i][j][1]=0.f; acc[i][j][2]=0.f; acc[i][j][3]=0.f; }

  for (int k0 = 0; k0 < CHN; k0 += 64) {
    __syncthreads();
#pragma unroll
    for (int i = 0; i < 8; ++i) {
      int p = 512 * wv + 64 * i + lane;
      int row = p >> 3, h = (p & 7) ^ (row & 7);
      gll16(wb + (size_t)row * CHN + k0 + h * 8, &As[(512 * wv + 64 * i) * 8]);
    }
    {  // x: 64x64 fp32->bf16, 2 chunks/thread
      int row = tid >> 2, hb = (tid & 3) * 2;
      const float* src = x + (t0 + row) * CHN + k0 + hb * 8;
      float4 f0 = *(const float4*)src;
      float4 f1 = *(const float4*)(src + 4);
      float4 f2 = *(const float4*)(src + 8);
      float4 f3 = *(const float4*)(src + 12);
      *(uint4*)&Bs[PERMC(row, hb)]     = packbf8(f0, f1);
      *(uint4*)&Bs[PERMC(row, hb + 1)] = packbf8(f2, f3);
    }
    __syncthreads();
#pragma unroll
    for (int ks = 0; ks < 2; ++ks) {
      s16x8 af[4], bfr[4];
#pragma unroll
      for (int mt = 0; mt < 4; ++mt) {
        int row = 64 * wv + 16 * mt + ln15;
        af[mt] = *(const s16x8*)&As[PERMC(row, ks * 4 + hf)];
      }
#pragma unroll
      for (int nt = 0; nt < 4; ++nt) {
        int row = 16 * nt + ln15;
        bfr[nt] = *(const s16x8*)&Bs[PERMC(row, ks * 4 + hf)];
      }
#pragma unroll
      for (int mt = 0; mt < 4; ++mt)
#pragma unroll
        for (int nt = 0; nt < 4; ++nt)
          acc[mt][nt] = MFMA16(af[mt], bfr[nt], acc[mt][nt]);
    }
  }
  // epilogue: D[m=cout][n=t]; col=lane&15=t, row=quad*4+r
  int quad = hf;
#pragma unroll
  for (int mt = 0; mt < 4; ++mt) {
#pragma unroll
    for (int r = 0; r < 4; ++r) {
      int row = 64 * wv + 16 * mt + 4 * quad + r;
      float bias = benc[row];
      float mv = 0.f;
#pragma unroll
      for (int nt = 0; nt < 4; ++nt) {
        float v = acc[mt][nt][r] + bias;
        int t = tin + 16 * nt + ln15;
        xeT[(size_t)(b * CHN + row) * XROW + PREPAD + t] = f2bf(v);
        mv = fmaxf(mv, fabsf(v));
      }
      mv = fmaxf(mv, __shfl_xor(mv, 1)); mv = fmaxf(mv, __shfl_xor(mv, 2));
      mv = fmaxf(mv, __shfl_xor(mv, 4)); mv = fmaxf(mv, __shfl_xor(mv, 8));
      if (ln15 == 0) atomicMax(&maxxe[b * CHN + row], __float_as_uint(mv));
    }
  }
}

// ------------- conv: y1[t][c] = gelu(FIR(xe) + h0*xe)
__global__ __launch_bounds__(512) void k_conv(const unsigned short* xeT,
                                              const unsigned short* afr,
                                              unsigned short* y1, const float* h0p) {
  __shared__ __align__(16) unsigned short xet[8 * CROW2]; // 32KB
  __shared__ __align__(16) unsigned short bnc[8 * CTP];   // 16.5KB
  int tid = threadIdx.x, lane = tid & 63, wv = tid >> 6;
  int idx = blockIdx.x;                          // grid 2048 = 8b x 32cg x 8tg
  int tg = idx & 7, cg = (idx >> 3) & 31, b = idx >> 8;
  int c0 = cg * 8, t0 = tg * CT2;
  int c = c0 + wv;

  s16x8 afrg[NDD];
  {
    const unsigned short* ap = afr + (size_t)c * (NDD * 512) + (size_t)lane * 8;
#pragma unroll
    for (int dd = 0; dd < NDD; ++dd)
      afrg[dd] = *(const s16x8*)(ap + (size_t)dd * 512);
  }
  {
    int lp = lane ^ ((lane >> 3) & 7);
    const unsigned short* gbase = xeT + (size_t)(b * CHN + c) * XROW + t0;
    unsigned short* lbase = &xet[wv * CROW2];
#pragma unroll
    for (int k = 0; k < 4; ++k)
      gll16(gbase + (size_t)(64 * k + lp) * 8, &lbase[k * 64 * 8]);
  }
  float h0 = h0p[0];

  int n = lane & 15, quad = lane >> 4;
  int qc = quad - ((quad >> 1) << 2);            // 0,1,-2,-1
  const char* xb = (const char*)&xet[wv * CROW2];

  int ad[NDD];
  {
    int cb0 = 2 * n + qc + 68;
#pragma unroll
    for (int dd = 0; dd < NDD; ++dd) {
      int cc = cb0 - 4 * dd;
      ad[dd] = (cc ^ ((cc >> 3) & 7)) * 16;
    }
  }
  int ead;
  {
    int ch = 68 + 2 * n + (quad >> 1);
    ead = (ch ^ ((ch >> 3) & 7)) * 16 + 8 * (quad & 1);
  }
  __syncthreads();

#pragma unroll 1
  for (int s = 0; s < 4; ++s) {
    f32x4 a0, a1;
    a0[0]=0.f; a0[1]=0.f; a0[2]=0.f; a0[3]=0.f;
    a1[0]=0.f; a1[1]=0.f; a1[2]=0.f; a1[3]=0.f;
#pragma unroll
    for (int dd = 0; dd < 16; dd += 2) {
      a0 = MFMA16(afrg[dd],     *(const s16x8*)(xb + ad[dd]),     a0);
      a1 = MFMA16(afrg[dd + 1], *(const s16x8*)(xb + ad[dd + 1]), a1);
    }
    a0 = MFMA16(afrg[16], *(const s16x8*)(xb + ad[16]), a0);
    uint2 xvp = *(const uint2*)(xb + ead);
    unsigned short o[4];
#pragma unroll
    for (int r = 0; r < 4; ++r) {
      float xv = bf2f(((const unsigned short*)&xvp)[r]);
      float v = (a0[r] + a1[r]) + h0 * xv;
      o[r] = f2bf(geluf(v));
    }
    uint2 pw;
    pw.x = (unsigned)o[0] | ((unsigned)o[1] << 16);
    pw.y = (unsigned)o[2] | ((unsigned)o[3] << 16);
    *(uint2*)&bnc[wv * CTP + 256 * s + 16 * n + 4 * quad] = pw;
#pragma unroll
    for (int dd = 16; dd >= 8; --dd) ad[dd] = ad[dd - 8];
#pragma unroll
    for (int dd = 0; dd < 8; ++dd) ad[dd] = (ad[dd] + 512) ^ 64;
    ead = (ead + 512) ^ 64;
  }
  __syncthreads();
  {
    const size_t obase = (size_t)(b * SEQ + t0) * CHN + c0;
    int tb = tid >> 1, h = (tid & 1) * 4;
#pragma unroll
    for (int s = 0; s < 4; ++s) {
      int tl = 256 * s + tb;
      uint2 pk;
      pk.x = (unsigned)bnc[(h + 0) * CTP + tl] | ((unsigned)bnc[(h + 1) * CTP + tl] << 16);
      pk.y = (unsigned)bnc[(h + 2) * CTP + tl] | ((unsigned)bnc[(h + 3) * CTP + tl] << 16);
      *(uint2*)(y1 + obase + (size_t)tl * CHN + h) = pk;
    }
  }
}

// ------ k_g23: fused GEMM2+GEMM3 (used ONLY when xeT is in ws -> race-free).
__global__ __launch_bounds__(256) void k_g23(const unsigned short* y1,
                                             const unsigned short* wfb, const float* bfc,
                                             const unsigned short* xeT, const float* gam,
                                             const float* bet,
                                             const unsigned short* wdb, const float* bd,
                                             float* yout, unsigned int* maxy) {
  __shared__ __align__(16) char smem[75776];
  unsigned short* Ws  = (unsigned short*)smem;            // 32768B W tile (perm)
  unsigned short* Asb = (unsigned short*)(smem + 32768);  //  8192B y1 tile (perm)
  float*          pl  = (float*)(smem + 40960);           //  1024B LN partials
  unsigned short* y2s = (unsigned short*)(smem + 41984);  // 33792B y2n [64][264]
  int tid = threadIdx.x, lane = tid & 63, wv = tid >> 6;
  int ln15 = lane & 15, hf = lane >> 4, quad = hf;
  size_t M0 = (size_t)blockIdx.x * 64;           // grid 1024
  int b = (int)(M0 >> 13), tin = (int)(M0 & 8191);
  int mh = wv & 1, nh = wv >> 1;
  f32x4 acc[2][8];
#pragma unroll
  for (int i = 0; i < 2; ++i)
#pragma unroll
    for (int j = 0; j < 8; ++j) { acc[i][j][0]=0.f; acc[i][j][1]=0.f; acc[i][j][2]=0.f; acc[i][j][3]=0.f; }

  // ---------------- phase 1: y2n = LN(gelu(y1 W_fc^T + b_fc) + xe)
  for (int k0 = 0; k0 < CHN; k0 += 64) {
    __syncthreads();
#pragma unroll
    for (int i = 0; i < 8; ++i) {               // W_fc: 2048 chunks
      int p = 512 * wv + 64 * i + lane;
      int row = p >> 3, h = (p & 7) ^ (row & 7);
      gll16(wfb + (size_t)row * CHN + k0 + h * 8, &Ws[(512 * wv + 64 * i) * 8]);
    }
#pragma unroll
    for (int i = 0; i < 2; ++i) {               // y1 A-tile: 512 chunks
      int p = 128 * wv + 64 * i + lane;
      int row = p >> 3, h = (p & 7) ^ (row & 7);
      gll16(y1 + (M0 + row) * CHN + k0 + h * 8, &Asb[(128 * wv + 64 * i) * 8]);
    }
    __syncthreads();
#pragma unroll
    for (int ks = 0; ks < 2; ++ks) {
      s16x8 af[2], bfr[8];
#pragma unroll
      for (int mt = 0; mt < 2; ++mt) {
        int row = 32 * mh + 16 * mt + ln15;
        af[mt] = *(const s16x8*)&Asb[PERMC(row, ks * 4 + hf)];
      }
#pragma unroll
      for (int nt = 0; nt < 8; ++nt) {
        int row = 128 * nh + 16 * nt + ln15;
        bfr[nt] = *(const s16x8*)&Ws[PERMC(row, ks * 4 + hf)];
      }
#pragma unroll
      for (int mt = 0; mt < 2; ++mt)
#pragma unroll
        for (int nt = 0; nt < 8; ++nt)
          acc[mt][nt] = MFMA16(af[mt], bfr[nt], acc[mt][nt]);
    }
  }
  float g8[8], be8[8], bf8[8];
#pragma unroll
  for (int nt = 0; nt < 8; ++nt) {
    int col = 128 * nh + 16 * nt + ln15;
    g8[nt] = gam[col]; be8[nt] = bet[col]; bf8[nt] = bfc[col];
  }
#pragma unroll
  for (int mt = 0; mt < 2; ++mt) {
    int mlb = 32 * mh + 16 * mt + 4 * quad;
    uint2 xv2[8];
#pragma unroll
    for (int nt = 0; nt < 8; ++nt) {            // xe skip: 4 consecutive t per lane
      int col = 128 * nh + 16 * nt + ln15;
      xv2[nt] = *(const uint2*)(xeT + (size_t)(b * CHN + col) * XROW + PREPAD + tin + mlb);
    }
#pragma unroll
    for (int r = 0; r < 4; ++r) {
      int ml = mlb + r;
      float s1 = 0.f, s2 = 0.f;
#pragma unroll
      for (int nt = 0; nt < 8; ++nt) {
        float t2 = acc[mt][nt][r] + bf8[nt];
        float xv = bf2f(((const unsigned short*)&xv2[nt])[r]);
        float y2 = geluf(t2) + xv;
        acc[mt][nt][r] = y2;
        s1 += y2; s2 += y2 * y2;
      }
      s1 += __shfl_xor(s1, 1); s2 += __shfl_xor(s2, 1);
      s1 += __shfl_xor(s1, 2); s2 += __shfl_xor(s2, 2);
      s1 += __shfl_xor(s1, 4); s2 += __shfl_xor(s2, 4);
      s1 += __shfl_xor(s1, 8); s2 += __shfl_xor(s2, 8);
      if (ln15 == 0) { pl[(ml * 2 + nh) * 2 + 0] = s1; pl[(ml * 2 + nh) * 2 + 1] = s2; }
    }
  }
  __syncthreads();
#pragma unroll
  for (int mt = 0; mt < 2; ++mt) {
#pragma unroll
    for (int r = 0; r < 4; ++r) {
      int ml = 32 * mh + 16 * mt + 4 * quad + r;
      float s1 = pl[(ml * 2 + 0) * 2 + 0] + pl[(ml * 2 + 1) * 2 + 0];
      float s2 = pl[(ml * 2 + 0) * 2 + 1] + pl[(ml * 2 + 1) * 2 + 1];
      float mu = s1 * (1.f / 256.f);
      float var = s2 * (1.f / 256.f) - mu * mu;
      float ri = rsqrtf(var + 1e-5f);
#pragma unroll
      for (int nt = 0; nt < 8; ++nt) {
        int col = 128 * nh + 16 * nt + ln15;
        float yn = (acc[mt][nt][r] - mu) * ri * g8[nt] + be8[nt];
        y2s[ml * 264 + col] = f2bf(yn);         // LDS, not HBM
      }
    }
  }

  // ---------------- phase 2: y = y2n W_dec^T + b_dec
  f32x4 ac2[2][8];
#pragma unroll
  for (int i = 0; i < 2; ++i)
#pragma unroll
    for (int j = 0; j < 8; ++j) { ac2[i][j][0]=0.f; ac2[i][j][1]=0.f; ac2[i][j][2]=0.f; ac2[i][j][3]=0.f; }

  for (int k0 = 0; k0 < CHN; k0 += 64) {
    __syncthreads();                            // Ws reuse + y2s visibility
#pragma unroll
    for (int i = 0; i < 8; ++i) {               // W_dec: 2048 chunks
      int p = 512 * wv + 64 * i + lane;
      int row = p >> 3, h = (p & 7) ^ (row & 7);
      gll16(wdb + (size_t)row * CHN + k0 + h * 8, &Ws[(512 * wv + 64 * i) * 8]);
    }
    __syncthreads();
#pragma unroll
    for (int ks = 0; ks < 2; ++ks) {
      s16x8 af[2], bfr[8];
#pragma unroll
      for (int mt = 0; mt < 2; ++mt) {
        int row = 32 * mh + 16 * mt + ln15;
        af[mt] = *(const s16x8*)&y2s[row * 264 + k0 + (ks * 4 + hf) * 8];
      }
#pragma unroll
      for (int nt = 0; nt < 8; ++nt) {
        int row = 128 * nh + 16 * nt + ln15;
        bfr[nt] = *(const s16x8*)&Ws[PERMC(row, ks * 4 + hf)];
      }
#pragma unroll
      for (int mt = 0; mt < 2; ++mt)
#pragma unroll
        for (int nt = 0; nt < 8; ++nt)
          ac2[mt][nt] = MFMA16(af[mt], bfr[nt], ac2[mt][nt]);
    }
  }
  float bd8[8];
#pragma unroll
  for (int nt = 0; nt < 8; ++nt) bd8[nt] = bd[128 * nh + 16 * nt + ln15];
#pragma unroll
  for (int mt = 0; mt < 2; ++mt)
#pragma unroll
    for (int r = 0; r < 4; ++r) {
      int ml = 32 * mh + 16 * mt + 4 * quad + r;
#pragma unroll
      for (int nt = 0; nt < 8; ++nt) {
        int col = 128 * nh + 16 * nt + ln15;
        float v = ac2[mt][nt][r] + bd8[nt];
        ac2[mt][nt][r] = v;
        yout[(M0 + ml) * CHN + col] = v;
      }
    }
#pragma unroll
  for (int nt = 0; nt < 8; ++nt) {
    int col = 128 * nh + 16 * nt + ln15;
    float mv = 0.f;
#pragma unroll
    for (int mt = 0; mt < 2; ++mt)
#pragma unroll
      for (int r = 0; r < 4; ++r) mv = fmaxf(mv, fabsf(ac2[mt][nt][r]));
    mv = fmaxf(mv, __shfl_xor(mv, 16));
    mv = fmaxf(mv, __shfl_xor(mv, 32));
    if (quad == 0) atomicMax(&maxy[b * CHN + col], __float_as_uint(mv));
  }
}

// ------ fallback split GEMM2 (R10, known-passing): y2n in-place into y1
__global__ __launch_bounds__(256) void k_gemm2(const unsigned short* y1,
                                               const unsigned short* wb, const float* bfc,
                                               const unsigned short* xeT, const float* gam,
                                               const float* bet, unsigned short* y2n) {
  __shared__ __align__(16) unsigned short Ws[256 * 64];
  __shared__ __align__(16) unsigned short Asb[64 * 64];
  __shared__ float pl[64][2][2];
  int tid = threadIdx.x, lane = tid & 63, wv = tid >> 6;
  int ln15 = lane & 15, hf = lane >> 4, quad = hf;
  size_t M0 = (size_t)blockIdx.x * 64;           // grid 1024
  int b = (int)(M0 >> 13), tin = (int)(M0 & 8191);
  int mh = wv & 1, nh = wv >> 1;
  f32x4 acc[2][8];
#pragma unroll
  for (int i = 0; i < 2; ++i)
#pragma unroll
    for (int j = 0; j < 8; ++j) { acc[i][j][0]=0.f; acc[i][j][1]=0.f; acc[i][j][2]=0.f; acc[i][j][3]=0.f; }

  for (int k0 = 0; k0 < CHN; k0 += 64) {
    __syncthreads();
#pragma unroll
    for (int i = 0; i < 8; ++i) {
      int p = 512 * wv + 64 * i + lane;
      int row = p >> 3, h = (p & 7) ^ (row & 7);
      gll16(wb + (size_t)row * CHN + k0 + h * 8, &Ws[(512 * wv + 64 * i) * 8]);
    }
#pragma unroll
    for (int i = 0; i < 2; ++i) {
      int p = 128 * wv + 64 * i + lane;
      int row = p >> 3, h = (p & 7) ^ (row & 7);
      gll16(y1 + (M0 + row) * CHN + k0 + h * 8, &Asb[(128 * wv + 64 * i) * 8]);
    }
    __syncthreads();
#pragma unroll
    for (int ks = 0; ks < 2; ++ks) {
      s16x8 af[2], bfr[8];
#pragma unroll
      for (int mt = 0; mt < 2; ++mt) {
        int row = 32 * mh + 16 * mt + ln15;
        af[mt] = *(const s16x8*)&Asb[PERMC(row, ks * 4 + hf)];
      }
#pragma unroll
      for (int nt = 0; nt < 8; ++nt) {
        int row = 128 * nh + 16 * nt + ln15;
        bfr[nt] = *(const s16x8*)&Ws[PERMC(row, ks * 4 + hf)];
      }
#pragma unroll
      for (int mt = 0; mt < 2; ++mt)
#pragma unroll
        for (int nt = 0; nt < 8; ++nt)
          acc[mt][nt] = MFMA16(af[mt], bfr[nt], acc[mt][nt]);
    }
  }
  float g8[8], be8[8], bf8[8];
#pragma unroll
  for (int nt = 0; nt < 8; ++nt) {
    int col = 128 * nh + 16 * nt + ln15;
    g8[nt] = gam[col]; be8[nt] = bet[col]; bf8[nt] = bfc[col];
  }
#pragma unroll
  for (int mt = 0; mt < 2; ++mt) {
    int mlb = 32 * mh + 16 * mt + 4 * quad;
    uint2 xv2[8];
#pragma unroll
    for (int nt = 0; nt < 8; ++nt) {
      int col = 128 * nh + 16 * nt + ln15;
      xv2[nt] = *(const uint2*)(xeT + (size_t)(b * CHN + col) * XROW + PREPAD + tin + mlb);
    }
#pragma unroll
    for (int r = 0; r < 4; ++r) {
      int ml = mlb + r;
      float s1 = 0.f, s2 = 0.f;
#pragma unroll
      for (int nt = 0; nt < 8; ++nt) {
        float t2 = acc[mt][nt][r] + bf8[nt];
        float xv = bf2f(((const unsigned short*)&xv2[nt])[r]);
        float y2 = geluf(t2) + xv;
        acc[mt][nt][r] = y2;
        s1 += y2; s2 += y2 * y2;
      }
      s1 += __shfl_xor(s1, 1); s2 += __shfl_xor(s2, 1);
      s1 += __shfl_xor(s1, 2); s2 += __shfl_xor(s2, 2);
      s1 += __shfl_xor(s1, 4); s2 += __shfl_xor(s2, 4);
      s1 += __shfl_xor(s1, 8); s2 += __shfl_xor(s2, 8);
      if (ln15 == 0) { pl[ml][nh][0] = s1; pl[ml][nh][1] = s2; }
    }
  }
  __syncthreads();
#pragma unroll
  for (int mt = 0; mt < 2; ++mt) {
#pragma unroll
    for (int r = 0; r < 4; ++r) {
      int ml = 32 * mh + 16 * mt + 4 * quad + r;
      float s1 = pl[ml][0][0] + pl[ml][1][0];
      float s2 = pl[ml][0][1] + pl[ml][1][1];
      float mu = s1 * (1.f / 256.f);
      float var = s2 * (1.f / 256.f) - mu * mu;
      float ri = rsqrtf(var + 1e-5f);
#pragma unroll
      for (int nt = 0; nt < 8; ++nt) {
        int col = 128 * nh + 16 * nt + ln15;
        float yn = (acc[mt][nt][r] - mu) * ri * g8[nt] + be8[nt];
        y2n[(M0 + ml) * CHN + col] = f2bf(yn);
      }
    }
  }
}

// ------ fallback split GEMM3 (R10, known-passing)
__global__ __launch_bounds__(256) void k_gemm3(const unsigned short* y2n,
                                               const unsigned short* wb, const float* bd,
                                               float* yout, unsigned int* maxy) {
  __shared__ __align__(16) unsigned short Ws[256 * 64];
  __shared__ __align__(16) unsigned short Asb[64 * 64];
  int tid = threadIdx.x, lane = tid & 63, wv = tid >> 6;
  int ln15 = lane & 15, hf = lane >> 4, quad = hf;
  size_t M0 = (size_t)blockIdx.x * 64;           // grid 1024
  int b = (int)(M0 >> 13);
  int mh = wv & 1, nh = wv >> 1;
  f32x4 acc[2][8];
#pragma unroll
  for (int i = 0; i < 2; ++i)
#pragma unroll
    for (int j = 0; j < 8; ++j) { acc[i][j][0]=0.f; acc[i][j][1]=0.f; acc[i][j][2]=0.f; acc[i][j][3]=0.f; }

  for (int k0 = 0; k0 < CHN; k0 += 64) {
    __syncthreads();
#pragma unroll
    for (int i = 0; i < 8; ++i) {
      int p = 512 * wv + 64 * i + lane;
      int row = p >> 3, h = (p & 7) ^ (row & 7);
      gll16(wb + (size_t)row * CHN + k0 + h * 8, &Ws[(512 * wv + 64 * i) * 8]);
    }
#pragma unroll
    for (int i = 0; i < 2; ++i) {
      int p = 128 * wv + 64 * i + lane;
      int row = p >> 3, h = (p & 7) ^ (row & 7);
      gll16(y2n + (M0 + row) * CHN + k0 + h * 8, &Asb[(128 * wv + 64 * i) * 8]);
    }
    __syncthreads();
#pragma unroll
    for (int ks = 0; ks < 2; ++ks) {
      s16x8 af[2], bfr[8];
#pragma unroll
      for (int mt = 0; mt < 2; ++mt) {
        int row = 32 * mh + 16 * mt + ln15;
        af[mt] = *(const s16x8*)&Asb[PERMC(row, ks * 4 + hf)];
      }
#pragma unroll
      for (int nt = 0; nt < 8; ++nt) {
        int row = 128 * nh + 16 * nt + ln15;
        bfr[nt] = *(const s16x8*)&Ws[PERMC(row, ks * 4 + hf)];
      }
#pragma unroll
      for (int mt = 0; mt < 2; ++mt)
#pragma unroll
        for (int nt = 0; nt < 8; ++nt)
          acc[mt][nt] = MFMA16(af[mt], bfr[nt], acc[mt][nt]);
    }
  }
  float bd8[8];
#pragma unroll
  for (int nt = 0; nt < 8; ++nt) bd8[nt] = bd[128 * nh + 16 * nt + ln15];
#pragma unroll
  for (int mt = 0; mt < 2; ++mt)
#pragma unroll
    for (int r = 0; r < 4; ++r) {
      int ml = 32 * mh + 16 * mt + 4 * quad + r;
#pragma unroll
      for (int nt = 0; nt < 8; ++nt) {
        int col = 128 * nh + 16 * nt + ln15;
        float v = acc[mt][nt][r] + bd8[nt];
        acc[mt][nt][r] = v;
        yout[(M0 + ml) * CHN + col] = v;
      }
    }
#pragma unroll
  for (int nt = 0; nt < 8; ++nt) {
    int col = 128 * nh + 16 * nt + ln15;
    float mv = 0.f;
#pragma unroll
    for (int mt = 0; mt < 2; ++mt)
#pragma unroll
      for (int r = 0; r < 4; ++r) mv = fmaxf(mv, fabsf(acc[mt][nt][r]));
    mv = fmaxf(mv, __shfl_xor(mv, 16));
    mv = fmaxf(mv, __shfl_xor(mv, 32));
    if (quad == 0) atomicMax(&maxy[b * CHN + col], __float_as_uint(mv));
  }
}

// ------------------------------------------------------------ h = my/(mx+eps)
__global__ __launch_bounds__(256) void k_hfin(const unsigned int* maxxe,
                                              const unsigned int* maxy, float* hout) {
  int i = blockIdx.x * 256 + threadIdx.x;        // grid 8
  if (i < BSZ * CHN) {
    float mx = __uint_as_float(maxxe[i]);
    float my = __uint_as_float(maxy[i]);
    hout[i] = my / (mx + 1e-6f);
  }
}

// ---------------------------------------------------------------------------
extern "C" void kernel_launch(void* const* d_in, const int* in_sizes, int n_in,
                              void* d_out, int out_size, void* d_ws, size_t ws_size,
                              hipStream_t stream) {
  const float* x   = (const float*)d_in[0];
  const float* A   = (const float*)d_in[1];
  const float* Bp  = (const float*)d_in[2];
  const float* h0  = (const float*)d_in[3];
  const float* We  = (const float*)d_in[4];
  const float* be  = (const float*)d_in[5];
  const float* Wf  = (const float*)d_in[6];
  const float* bfc = (const float*)d_in[7];
  const float* gam = (const float*)d_in[8];
  const float* bet = (const float*)d_in[9];
  const float* Wd  = (const float*)d_in[10];
  const float* bd  = (const float*)d_in[11];

  char* ws = (char*)d_ws;
  unsigned short* y1  = (unsigned short*)(ws + 0);          // 33554432 B
  unsigned short* afr = (unsigned short*)(ws + 33554432);   //  4456448 B
  unsigned short* web = (unsigned short*)(ws + 38010880);   //   131072 B
  unsigned short* wfb = (unsigned short*)(ws + 38141952);
  unsigned short* wdb = (unsigned short*)(ws + 38273024);
  unsigned int*  maxxe = (unsigned int*)(ws + 38404096);    //     8192 B
  unsigned int*  maxy  = (unsigned int*)(ws + 38412288);    //     8192 B
  // optional xeT region (big-ws path): 35782656 B -> total 74203136 B
  const size_t XET_OFF = 38420480;
  const size_t WS_NEED = XET_OFF + (size_t)2048 * XROW * 2; // 74,203,136

  float* yout = (float*)d_out;
  float* hout = yout + YELEMS;

  int big = (ws_size >= WS_NEED);
  unsigned short* xeT = big ? (unsigned short*)(ws + XET_OFF)
                            : (unsigned short*)d_out;       // legacy aliasing

  k_pzk<<<690, 512, 0, stream>>>(A, Bp, afr, We, Wf, Wd, web, wfb, wdb,
                                 xeT, (uint4*)maxxe);
  k_gemm1<<<1024, 256, 0, stream>>>(x, web, be, xeT, maxxe);
  k_conv<<<2048, 512, 0, stream>>>(xeT, afr, y1, h0);
  if (big) {
    k_g23<<<1024, 256, 0, stream>>>(y1, wfb, bfc, xeT, gam, bet, wdb, bd,
                                    yout, maxy);
  } else {
    k_gemm2<<<1024, 256, 0, stream>>>(y1, wfb, bfc, xeT, gam, bet, y1);
    k_gemm3<<<1024, 256, 0, stream>>>(y1, wdb, bd, yout, maxy);
  }
  k_hfin<<<8, 256, 0, stream>>>(maxxe, maxy, hout);
}

// Round 8
// 285.688 us; speedup vs baseline: 1.1308x; 1.1308x over previous
//
#include <hip/hip_runtime.h>
#include <math.h>

// ---------------------------------------------------------------------------
// RTF-SSM block, MI355X. FFT path replaced by:
//   K = impulse response of B(z)/A(z), truncated at 512 taps (Newton
//   power-series inversion, 9 wave-parallel doubling steps).
//   causal conv = Toeplitz-block bf16 MFMA (16x16x32), A-frags prebuilt.
//   GEMMs (65536x256x256) bf16 MFMA with fused bias/gelu/skip/LN/max.
// R6: VALU diet in k_conv (gelu via exp2+rcp, sliding swizzled LDS addrs).
// R9: kgen dual-G/uniform-b128 body (passed R4/R5/R12).
// R10: conv 8ch x 1024t blocks (16B-granular y1 stores).
// R13: ledger reconciliation across rounds showed (a) kgen is STILL a
//   ~50us serial chain hiding just under every top-5 cutoff, (b) the best
//   total (R2, 279.6) came from fusing kgen INTO gemm1's launch (marginal
//   cost ~21us vs ~55 standalone), (c) xeT-in-d_out placement beat ws.
//   This round: R2 structure + kgen8 math at 4 waves/256thr fused into
//   k_g1k blocks [0,64); split gemm2/gemm3 (keeps d_out aliasing race-free);
//   conv unchanged (R10). g23 fusion shelved.
// ---------------------------------------------------------------------------

#define BSZ   8
#define SEQ   8192
#define CHN   256
#define ORD   64
#define STAPS 512
#define NDD   17            // d-pairs: covers d = 0..33 (taps to 543 >= 511)
#define PREPAD 544          // history prepad (>= 528 needed), 16-aligned
#define XROW  (PREPAD + SEQ) // 8736 elems per (b,c) row of xe^T
#define MTOT  (BSZ * SEQ)   // 65536
#define YELEMS (MTOT * CHN) // 16777216

#define CT2   1024          // conv t-tile per block
#define CTP   1032          // conv bnc row stride (8-short pad)
#define CROW2 2048          // conv xet row elems (4 x 512 staged)

typedef short s16x8 __attribute__((ext_vector_type(8)));
typedef float f32x4 __attribute__((ext_vector_type(4)));

#define MFMA16(a, b, c) __builtin_amdgcn_mfma_f32_16x16x32_bf16((a), (b), (c), 0, 0, 0)

// async global->LDS 16B: LDS dest = wave-uniform base + lane*16
__device__ __forceinline__ void gll16(const void* g, void* l) {
  __builtin_amdgcn_global_load_lds(
      (const __attribute__((address_space(1))) unsigned int*)g,
      (__attribute__((address_space(3))) unsigned int*)l, 16, 0, 0);
}

// XOR-perm chunk layout: chunk p of (row,h) stored at elems PERMC
#define PERMC(row, h) (((row) * 8 + ((h) ^ ((row) & 7))) * 8)

__device__ __forceinline__ unsigned short f2bf(float f) {
  unsigned u = __float_as_uint(f);
  return (unsigned short)((u + 0x7FFFu + ((u >> 16) & 1u)) >> 16);
}
__device__ __forceinline__ float bf2f(unsigned short h) {
  return __uint_as_float(((unsigned)h) << 16);
}
// tanh-form gelu: x * sigmoid(2*sqrt(2/pi)*(x + 0.044715 x^3)).
// |err| vs exact erf-gelu < ~2e-4, << bf16 noise.
__device__ __forceinline__ float geluf(float x) {
  float x2 = x * x;
  float y = x * __builtin_fmaf(0.0356774081f, x2, 0.7978845608f);
  float e = __builtin_amdgcn_exp2f(-2.8853900818f * y);  // exp(-2y)
  return x * __builtin_amdgcn_rcpf(1.0f + e);
}
__device__ __forceinline__ uint4 packbf8(float4 a, float4 b) {
  uint4 r;
  r.x = (unsigned)f2bf(a.x) | ((unsigned)f2bf(a.y) << 16);
  r.y = (unsigned)f2bf(a.z) | ((unsigned)f2bf(a.w) << 16);
  r.z = (unsigned)f2bf(b.x) | ((unsigned)f2bf(b.y) << 16);
  r.w = (unsigned)f2bf(b.z) | ((unsigned)f2bf(b.w) << 16);
  return r;
}

// -------------------------------------- fused: weights->bf16 + zero prepads
__global__ __launch_bounds__(256) void k_pz(const float* we, const float* wf,
                                            const float* wd, unsigned short* owe,
                                            unsigned short* owf, unsigned short* owd,
                                            unsigned short* xeT, uint4* maxbufs) {
  int bx = blockIdx.x, tid = threadIdx.x;     // grid 1316 = 768 prep + 548 zero
  if (bx < 768) {
    int i = bx * 256 + tid;
    int which = i >> 16, off = i & 65535;
    if (which == 0)      owe[off] = f2bf(we[off]);
    else if (which == 1) owf[off] = f2bf(wf[off]);
    else                 owd[off] = f2bf(wd[off]);
  } else {
    int i = (bx - 768) * 256 + tid;
    uint4 z; z.x = 0; z.y = 0; z.z = 0; z.w = 0;
    if (i < 2048 * 68) {                      // 544 elems/row = 68 x 16B chunks
      int row = i / 68, cc = i % 68;
      *(uint4*)((char*)xeT + (size_t)row * (XROW * 2) + (size_t)cc * 16) = z;
    } else {
      int j = i - 2048 * 68;
      if (j < 1024) maxbufs[j] = z;           // maxxe (8KB) + maxy (8KB)
    }
  }
}

// ---------------- K-gen: Newton inversion of A(z), one wave per channel,
// 4 waves/block (256 thr, fused into gemm1 launch). Dual shifted G copies
// for aligned b64 per-lane reads; uniform b128 coeff reads; zero-padded
// fixed-64 loops. No barriers (per-wave private LDS slices). Math identical
// to the 3x-passing kgen8 body.
__device__ __forceinline__ void kgen4(float* smemk, const float* A, const float* Bp,
                                      unsigned short* afr, int blk) {
  int tid = threadIdx.x, lane = tid & 63, wv = tid >> 6;   // wv in [0,4)
  int c = blk * 4 + wv;
  float* base = smemk + wv * 1872;            // 4 waves x 7488B = 29952B
  float* G0 = base;                           // [584], G0[64+t] = G[t]
  float* G1 = base + 584;                     // [584], G1[65+t] = G[t]
  float* Et = base + 1168;                    // [64]
  float* Asl = base + 1232;                   // [64]
  float* Bsl = base + 1296;                   // [64]
  float* Kb = base + 1360;                    // [512]

  Asl[lane] = A[(size_t)c * ORD + lane];      // a[u] = Asl[u-1], u in [1,64]
  Bsl[lane] = Bp[(size_t)c * ORD + lane];
  for (int i = lane; i < 1168; i += 64) base[i] = 0.f;  // zero both G copies
  if (lane == 0) { G0[64] = 1.f; G1[65] = 1.f; }        // G[0] = 1

  for (int n = 1; n < STAPS; n <<= 1) {
    int par = (n + lane) & 1;
    const float* Gc = par ? G1 : G0;
    int I0 = 64 + n + lane + par;             // even
    float e0 = 0.f, e1 = 0.f, e2 = 0.f, e3 = 0.f;
#pragma unroll
    for (int g = 0; g < 16; ++g) {
      float4 av = *(const float4*)&Asl[4 * g];
      float2 vA = *(const float2*)&Gc[I0 - 4 * g - 2];
      float2 vB = *(const float2*)&Gc[I0 - 4 * g - 4];
      e0 += av.x * vA.y;                      // u = 4g+1
      e1 += av.y * vA.x;                      // u = 4g+2
      e2 += av.z * vB.y;                      // u = 4g+3
      e3 += av.w * vB.x;                      // u = 4g+4
    }
    Et[lane] = (e0 + e1) + (e2 + e3);
    int nk = (n + 63) >> 6;
    for (int k = 0; k < nk; ++k) {
      int idx = k * 64 + lane;
      int parU = (idx + 1) & 1;
      const float* Gu = parU ? G1 : G0;
      int J0 = 64 + idx - 1 + parU;           // even
      float a0 = 0.f, a1 = 0.f, a2 = 0.f, a3 = 0.f;
#pragma unroll
      for (int g = 0; g < 16; ++g) {
        float4 ev = *(const float4*)&Et[4 * g];
        float2 vA = *(const float2*)&Gu[J0 - 4 * g];
        float2 vB = *(const float2*)&Gu[J0 - 4 * g - 2];
        a0 += ev.x * vA.y;                    // i = 4g
        a1 += ev.y * vA.x;                    // i = 4g+1
        a2 += ev.z * vB.y;                    // i = 4g+2
        a3 += ev.w * vB.x;                    // i = 4g+3
      }
      if (idx < n) {
        float gv = -((a0 + a1) + (a2 + a3));
        G0[64 + n + idx] = gv;
        G1[65 + n + idx] = gv;
      }
    }
  }

  for (int k = 0; k < 8; ++k) {
    int t = k * 64 + lane;
    int parB = (t + 1) & 1;
    const float* Gb = parB ? G1 : G0;
    int J0 = 64 + t - 1 + parB;               // even
    float a0 = 0.f, a1 = 0.f, a2 = 0.f, a3 = 0.f;
#pragma unroll
    for (int g = 0; g < 16; ++g) {
      float4 bv = *(const float4*)&Bsl[4 * g];
      float2 vA = *(const float2*)&Gb[J0 - 4 * g];
      float2 vB = *(const float2*)&Gb[J0 - 4 * g - 2];
      a0 += bv.x * vA.y;                      // j = 4g
      a1 += bv.y * vA.x;                      // j = 4g+1
      a2 += bv.z * vB.y;                      // j = 4g+2
      a3 += bv.w * vB.x;                      // j = 4g+3
    }
    Kb[t] = (a0 + a1) + (a2 + a3);
  }

  int m = lane & 15, quad = lane >> 4;
  for (int dd = 0; dd < NDD; ++dd) {
    unsigned short v[8];
#pragma unroll
    for (int j = 0; j < 8; ++j) {
      int k = quad * 8 + j;
      int d = 2 * dd + (k >> 4);
      int p = k & 15;
      int s = 16 * d + m - p;
      float kv = (s >= 0 && s < STAPS) ? Kb[s] : 0.f;
      v[j] = f2bf(kv);
    }
    uint4 pk;
    pk.x = (unsigned)v[0] | ((unsigned)v[1] << 16);
    pk.y = (unsigned)v[2] | ((unsigned)v[3] << 16);
    pk.z = (unsigned)v[4] | ((unsigned)v[5] << 16);
    pk.w = (unsigned)v[6] | ((unsigned)v[7] << 16);
    *(uint4*)(afr + ((size_t)(c * NDD + dd) * 64 + lane) * 8) = pk;
  }
}

// --------------- fused GEMM1 + kgen: blocks [0,64) = kgen, [64,1088) = GEMM1
// GEMM1 (transposed out): xe^T[cout][t] = W_enc x^T + b_enc
// block: 256 cout x 64 t; BK=64; W via global_load_lds, direct-store epilogue.
__global__ __launch_bounds__(256) void k_g1k(const float* A, const float* Bp,
                                             unsigned short* afr,
                                             const float* x, const unsigned short* wb,
                                             const float* benc, unsigned short* xeT,
                                             unsigned int* maxxe) {
  __shared__ __align__(16) char smem[40960];  // union: gemm1 40960B / kgen 29952B
  if (blockIdx.x < 64) {
    kgen4((float*)smem, A, Bp, afr, blockIdx.x);
    return;
  }
  unsigned short* As = (unsigned short*)smem;           // W tile, perm layout
  unsigned short* Bs = (unsigned short*)(smem + 32768); // x tile, perm layout
  int tid = threadIdx.x, lane = tid & 63, wv = tid >> 6;
  int ln15 = lane & 15, hf = lane >> 4;
  size_t t0 = (size_t)(blockIdx.x - 64) * 64; // 1024 gemm blocks
  int b = (int)(t0 >> 13), tin = (int)(t0 & 8191);
  f32x4 acc[4][4];
#pragma unroll
  for (int i = 0; i < 4; ++i)
#pragma unroll
    for (int j = 0; j < 4; ++j) { acc[i][j][0]=0.f; acc[i][j][1]=0.f; acc[i][j][2]=0.f; acc[i][j][3]=0.f; }

  for (int k0 = 0; k0 < CHN; k0 += 64) {
    __syncthreads();
#pragma unroll
    for (int i = 0; i < 8; ++i) {
      int p = 512 * wv + 64 * i + lane;
      int row = p >> 3, h = (p & 7) ^ (row & 7);
      gll16(wb + (size_t)row * CHN + k0 + h * 8, &As[(512 * wv + 64 * i) * 8]);
    }
    {  // x: 64x64 fp32->bf16, 2 chunks/thread
      int row = tid >> 2, hb = (tid & 3) * 2;
      const float* src = x + (t0 + row) * CHN + k0 + hb * 8;
      float4 f0 = *(const float4*)src;
      float4 f1 = *(const float4*)(src + 4);
      float4 f2 = *(const float4*)(src + 8);
      float4 f3 = *(const float4*)(src + 12);
      *(uint4*)&Bs[PERMC(row, hb)]     = packbf8(f0, f1);
      *(uint4*)&Bs[PERMC(row, hb + 1)] = packbf8(f2, f3);
    }
    __syncthreads();
#pragma unroll
    for (int ks = 0; ks < 2; ++ks) {
      s16x8 af[4], bfr[4];
#pragma unroll
      for (int mt = 0; mt < 4; ++mt) {
        int row = 64 * wv + 16 * mt + ln15;
        af[mt] = *(const s16x8*)&As[PERMC(row, ks * 4 + hf)];
      }
#pragma unroll
      for (int nt = 0; nt < 4; ++nt) {
        int row = 16 * nt + ln15;
        bfr[nt] = *(const s16x8*)&Bs[PERMC(row, ks * 4 + hf)];
      }
#pragma unroll
      for (int mt = 0; mt < 4; ++mt)
#pragma unroll
        for (int nt = 0; nt < 4; ++nt)
          acc[mt][nt] = MFMA16(af[mt], bfr[nt], acc[mt][nt]);
    }
  }
  // epilogue: D[m=cout][n=t]; col=lane&15=t, row=quad*4+r
  int quad = hf;
#pragma unroll
  for (int mt = 0; mt < 4; ++mt) {
#pragma unroll
    for (int r = 0; r < 4; ++r) {
      int row = 64 * wv + 16 * mt + 4 * quad + r;
      float bias = benc[row];
      float mv = 0.f;
#pragma unroll
      for (int nt = 0; nt < 4; ++nt) {
        float v = acc[mt][nt][r] + bias;
        int t = tin + 16 * nt + ln15;
        xeT[(size_t)(b * CHN + row) * XROW + PREPAD + t] = f2bf(v);
        mv = fmaxf(mv, fabsf(v));
      }
      mv = fmaxf(mv, __shfl_xor(mv, 1)); mv = fmaxf(mv, __shfl_xor(mv, 2));
      mv = fmaxf(mv, __shfl_xor(mv, 4)); mv = fmaxf(mv, __shfl_xor(mv, 8));
      if (ln15 == 0) atomicMax(&maxxe[b * CHN + row], __float_as_uint(mv));
    }
  }
}

// ------------- conv: y1[t][c] = gelu(FIR(xe) + h0*xe)
// block = 8 ch x 1024 t (512 thr, 8 waves, wave owns 1 channel);
// A-frags in VGPRs; swizzled LDS addrs slide (rotate-8 + (a+512)^64).
__global__ __launch_bounds__(512) void k_conv(const unsigned short* xeT,
                                              const unsigned short* afr,
                                              unsigned short* y1, const float* h0p) {
  __shared__ __align__(16) unsigned short xet[8 * CROW2]; // 32KB
  __shared__ __align__(16) unsigned short bnc[8 * CTP];   // 16.5KB
  int tid = threadIdx.x, lane = tid & 63, wv = tid >> 6;
  int idx = blockIdx.x;                          // grid 2048 = 8b x 32cg x 8tg
  int tg = idx & 7, cg = (idx >> 3) & 31, b = idx >> 8;
  int c0 = cg * 8, t0 = tg * CT2;
  int c = c0 + wv;

  s16x8 afrg[NDD];
  {
    const unsigned short* ap = afr + (size_t)c * (NDD * 512) + (size_t)lane * 8;
#pragma unroll
    for (int dd = 0; dd < NDD; ++dd)
      afrg[dd] = *(const s16x8*)(ap + (size_t)dd * 512);
  }
  {
    int lp = lane ^ ((lane >> 3) & 7);
    const unsigned short* gbase = xeT + (size_t)(b * CHN + c) * XROW + t0;
    unsigned short* lbase = &xet[wv * CROW2];
#pragma unroll
    for (int k = 0; k < 4; ++k)
      gll16(gbase + (size_t)(64 * k + lp) * 8, &lbase[k * 64 * 8]);
  }
  float h0 = h0p[0];

  int n = lane & 15, quad = lane >> 4;
  int qc = quad - ((quad >> 1) << 2);            // 0,1,-2,-1
  const char* xb = (const char*)&xet[wv * CROW2];

  int ad[NDD];
  {
    int cb0 = 2 * n + qc + 68;
#pragma unroll
    for (int dd = 0; dd < NDD; ++dd) {
      int cc = cb0 - 4 * dd;
      ad[dd] = (cc ^ ((cc >> 3) & 7)) * 16;
    }
  }
  int ead;
  {
    int ch = 68 + 2 * n + (quad >> 1);
    ead = (ch ^ ((ch >> 3) & 7)) * 16 + 8 * (quad & 1);
  }
  __syncthreads();

#pragma unroll 1
  for (int s = 0; s < 4; ++s) {
    f32x4 a0, a1;
    a0[0]=0.f; a0[1]=0.f; a0[2]=0.f; a0[3]=0.f;
    a1[0]=0.f; a1[1]=0.f; a1[2]=0.f; a1[3]=0.f;
#pragma unroll
    for (int dd = 0; dd < 16; dd += 2) {
      a0 = MFMA16(afrg[dd],     *(const s16x8*)(xb + ad[dd]),     a0);
      a1 = MFMA16(afrg[dd + 1], *(const s16x8*)(xb + ad[dd + 1]), a1);
    }
    a0 = MFMA16(afrg[16], *(const s16x8*)(xb + ad[16]), a0);
    uint2 xvp = *(const uint2*)(xb + ead);
    unsigned short o[4];
#pragma unroll
    for (int r = 0; r < 4; ++r) {
      float xv = bf2f(((const unsigned short*)&xvp)[r]);
      float v = (a0[r] + a1[r]) + h0 * xv;
      o[r] = f2bf(geluf(v));
    }
    uint2 pw;
    pw.x = (unsigned)o[0] | ((unsigned)o[1] << 16);
    pw.y = (unsigned)o[2] | ((unsigned)o[3] << 16);
    *(uint2*)&bnc[wv * CTP + 256 * s + 16 * n + 4 * quad] = pw;
#pragma unroll
    for (int dd = 16; dd >= 8; --dd) ad[dd] = ad[dd - 8];
#pragma unroll
    for (int dd = 0; dd < 8; ++dd) ad[dd] = (ad[dd] + 512) ^ 64;
    ead = (ead + 512) ^ 64;
  }
  __syncthreads();
  {
    const size_t obase = (size_t)(b * SEQ + t0) * CHN + c0;
    int tb = tid >> 1, h = (tid & 1) * 4;
#pragma unroll
    for (int s = 0; s < 4; ++s) {
      int tl = 256 * s + tb;
      uint2 pk;
      pk.x = (unsigned)bnc[(h + 0) * CTP + tl] | ((unsigned)bnc[(h + 1) * CTP + tl] << 16);
      pk.y = (unsigned)bnc[(h + 2) * CTP + tl] | ((unsigned)bnc[(h + 3) * CTP + tl] << 16);
      *(uint2*)(y1 + obase + (size_t)tl * CHN + h) = pk;
    }
  }
}

// ------ GEMM2: y2n = LN(gelu(y1 W_fc^T + b_fc) + xe)*gamma+beta, in-place y1
__global__ __launch_bounds__(256) void k_gemm2(const unsigned short* y1,
                                               const unsigned short* wb, const float* bfc,
                                               const unsigned short* xeT, const float* gam,
                                               const float* bet, unsigned short* y2n) {
  __shared__ __align__(16) unsigned short Ws[256 * 64];
  __shared__ __align__(16) unsigned short Asb[64 * 64];
  __shared__ float pl[64][2][2];
  int tid = threadIdx.x, lane = tid & 63, wv = tid >> 6;
  int ln15 = lane & 15, hf = lane >> 4, quad = hf;
  size_t M0 = (size_t)blockIdx.x * 64;           // grid 1024
  int b = (int)(M0 >> 13), tin = (int)(M0 & 8191);
  int mh = wv & 1, nh = wv >> 1;
  f32x4 acc[2][8];
#pragma unroll
  for (int i = 0; i < 2; ++i)
#pragma unroll
    for (int j = 0; j < 8; ++j) { acc[i][j][0]=0.f; acc[i][j][1]=0.f; acc[i][j][2]=0.f; acc[i][j][3]=0.f; }

  for (int k0 = 0; k0 < CHN; k0 += 64) {
    __syncthreads();
#pragma unroll
    for (int i = 0; i < 8; ++i) {
      int p = 512 * wv + 64 * i + lane;
      int row = p >> 3, h = (p & 7) ^ (row & 7);
      gll16(wb + (size_t)row * CHN + k0 + h * 8, &Ws[(512 * wv + 64 * i) * 8]);
    }
#pragma unroll
    for (int i = 0; i < 2; ++i) {
      int p = 128 * wv + 64 * i + lane;
      int row = p >> 3, h = (p & 7) ^ (row & 7);
      gll16(y1 + (M0 + row) * CHN + k0 + h * 8, &Asb[(128 * wv + 64 * i) * 8]);
    }
    __syncthreads();
#pragma unroll
    for (int ks = 0; ks < 2; ++ks) {
      s16x8 af[2], bfr[8];
#pragma unroll
      for (int mt = 0; mt < 2; ++mt) {
        int row = 32 * mh + 16 * mt + ln15;
        af[mt] = *(const s16x8*)&Asb[PERMC(row, ks * 4 + hf)];
      }
#pragma unroll
      for (int nt = 0; nt < 8; ++nt) {
        int row = 128 * nh + 16 * nt + ln15;
        bfr[nt] = *(const s16x8*)&Ws[PERMC(row, ks * 4 + hf)];
      }
#pragma unroll
      for (int mt = 0; mt < 2; ++mt)
#pragma unroll
        for (int nt = 0; nt < 8; ++nt)
          acc[mt][nt] = MFMA16(af[mt], bfr[nt], acc[mt][nt]);
    }
  }
  float g8[8], be8[8], bf8[8];
#pragma unroll
  for (int nt = 0; nt < 8; ++nt) {
    int col = 128 * nh + 16 * nt + ln15;
    g8[nt] = gam[col]; be8[nt] = bet[col]; bf8[nt] = bfc[col];
  }
#pragma unroll
  for (int mt = 0; mt < 2; ++mt) {
    int mlb = 32 * mh + 16 * mt + 4 * quad;
    uint2 xv2[8];
#pragma unroll
    for (int nt = 0; nt < 8; ++nt) {
      int col = 128 * nh + 16 * nt + ln15;
      xv2[nt] = *(const uint2*)(xeT + (size_t)(b * CHN + col) * XROW + PREPAD + tin + mlb);
    }
#pragma unroll
    for (int r = 0; r < 4; ++r) {
      int ml = mlb + r;
      float s1 = 0.f, s2 = 0.f;
#pragma unroll
      for (int nt = 0; nt < 8; ++nt) {
        float t2 = acc[mt][nt][r] + bf8[nt];
        float xv = bf2f(((const unsigned short*)&xv2[nt])[r]);
        float y2 = geluf(t2) + xv;
        acc[mt][nt][r] = y2;
        s1 += y2; s2 += y2 * y2;
      }
      s1 += __shfl_xor(s1, 1); s2 += __shfl_xor(s2, 1);
      s1 += __shfl_xor(s1, 2); s2 += __shfl_xor(s2, 2);
      s1 += __shfl_xor(s1, 4); s2 += __shfl_xor(s2, 4);
      s1 += __shfl_xor(s1, 8); s2 += __shfl_xor(s2, 8);
      if (ln15 == 0) { pl[ml][nh][0] = s1; pl[ml][nh][1] = s2; }
    }
  }
  __syncthreads();
#pragma unroll
  for (int mt = 0; mt < 2; ++mt) {
#pragma unroll
    for (int r = 0; r < 4; ++r) {
      int ml = 32 * mh + 16 * mt + 4 * quad + r;
      float s1 = pl[ml][0][0] + pl[ml][1][0];
      float s2 = pl[ml][0][1] + pl[ml][1][1];
      float mu = s1 * (1.f / 256.f);
      float var = s2 * (1.f / 256.f) - mu * mu;
      float ri = rsqrtf(var + 1e-5f);
#pragma unroll
      for (int nt = 0; nt < 8; ++nt) {
        int col = 128 * nh + 16 * nt + ln15;
        float yn = (acc[mt][nt][r] - mu) * ri * g8[nt] + be8[nt];
        y2n[(M0 + ml) * CHN + col] = f2bf(yn);
      }
    }
  }
}

// ------------------- GEMM3: y = y2n W_dec^T + b_dec (fp32 out) + maxy atomics
__global__ __launch_bounds__(256) void k_gemm3(const unsigned short* y2n,
                                               const unsigned short* wb, const float* bd,
                                               float* yout, unsigned int* maxy) {
  __shared__ __align__(16) unsigned short Ws[256 * 64];
  __shared__ __align__(16) unsigned short Asb[64 * 64];
  int tid = threadIdx.x, lane = tid & 63, wv = tid >> 6;
  int ln15 = lane & 15, hf = lane >> 4, quad = hf;
  size_t M0 = (size_t)blockIdx.x * 64;           // grid 1024
  int b = (int)(M0 >> 13);
  int mh = wv & 1, nh = wv >> 1;
  f32x4 acc[2][8];
#pragma unroll
  for (int i = 0; i < 2; ++i)
#pragma unroll
    for (int j = 0; j < 8; ++j) { acc[i][j][0]=0.f; acc[i][j][1]=0.f; acc[i][j][2]=0.f; acc[i][j][3]=0.f; }

  for (int k0 = 0; k0 < CHN; k0 += 64) {
    __syncthreads();
#pragma unroll
    for (int i = 0; i < 8; ++i) {
      int p = 512 * wv + 64 * i + lane;
      int row = p >> 3, h = (p & 7) ^ (row & 7);
      gll16(wb + (size_t)row * CHN + k0 + h * 8, &Ws[(512 * wv + 64 * i) * 8]);
    }
#pragma unroll
    for (int i = 0; i < 2; ++i) {
      int p = 128 * wv + 64 * i + lane;
      int row = p >> 3, h = (p & 7) ^ (row & 7);
      gll16(y2n + (M0 + row) * CHN + k0 + h * 8, &Asb[(128 * wv + 64 * i) * 8]);
    }
    __syncthreads();
#pragma unroll
    for (int ks = 0; ks < 2; ++ks) {
      s16x8 af[2], bfr[8];
#pragma unroll
      for (int mt = 0; mt < 2; ++mt) {
        int row = 32 * mh + 16 * mt + ln15;
        af[mt] = *(const s16x8*)&Asb[PERMC(row, ks * 4 + hf)];
      }
#pragma unroll
      for (int nt = 0; nt < 8; ++nt) {
        int row = 128 * nh + 16 * nt + ln15;
        bfr[nt] = *(const s16x8*)&Ws[PERMC(row, ks * 4 + hf)];
      }
#pragma unroll
      for (int mt = 0; mt < 2; ++mt)
#pragma unroll
        for (int nt = 0; nt < 8; ++nt)
          acc[mt][nt] = MFMA16(af[mt], bfr[nt], acc[mt][nt]);
    }
  }
  float bd8[8];
#pragma unroll
  for (int nt = 0; nt < 8; ++nt) bd8[nt] = bd[128 * nh + 16 * nt + ln15];
#pragma unroll
  for (int mt = 0; mt < 2; ++mt)
#pragma unroll
    for (int r = 0; r < 4; ++r) {
      int ml = 32 * mh + 16 * mt + 4 * quad + r;
#pragma unroll
      for (int nt = 0; nt < 8; ++nt) {
        int col = 128 * nh + 16 * nt + ln15;
        float v = acc[mt][nt][r] + bd8[nt];
        acc[mt][nt][r] = v;
        yout[(M0 + ml) * CHN + col] = v;
      }
    }
#pragma unroll
  for (int nt = 0; nt < 8; ++nt) {
    int col = 128 * nh + 16 * nt + ln15;
    float mv = 0.f;
#pragma unroll
    for (int mt = 0; mt < 2; ++mt)
#pragma unroll
      for (int r = 0; r < 4; ++r) mv = fmaxf(mv, fabsf(acc[mt][nt][r]));
    mv = fmaxf(mv, __shfl_xor(mv, 16));
    mv = fmaxf(mv, __shfl_xor(mv, 32));
    if (quad == 0) atomicMax(&maxy[b * CHN + col], __float_as_uint(mv));
  }
}

// ------------------------------------------------------------ h = my/(mx+eps)
__global__ __launch_bounds__(256) void k_hfin(const unsigned int* maxxe,
                                              const unsigned int* maxy, float* hout) {
  int i = blockIdx.x * 256 + threadIdx.x;        // grid 8
  if (i < BSZ * CHN) {
    float mx = __uint_as_float(maxxe[i]);
    float my = __uint_as_float(maxy[i]);
    hout[i] = my / (mx + 1e-6f);
  }
}

// ---------------------------------------------------------------------------
extern "C" void kernel_launch(void* const* d_in, const int* in_sizes, int n_in,
                              void* d_out, int out_size, void* d_ws, size_t ws_size,
                              hipStream_t stream) {
  const float* x   = (const float*)d_in[0];
  const float* A   = (const float*)d_in[1];
  const float* Bp  = (const float*)d_in[2];
  const float* h0  = (const float*)d_in[3];
  const float* We  = (const float*)d_in[4];
  const float* be  = (const float*)d_in[5];
  const float* Wf  = (const float*)d_in[6];
  const float* bfc = (const float*)d_in[7];
  const float* gam = (const float*)d_in[8];
  const float* bet = (const float*)d_in[9];
  const float* Wd  = (const float*)d_in[10];
  const float* bd  = (const float*)d_in[11];

  char* ws = (char*)d_ws;
  unsigned short* y1  = (unsigned short*)(ws + 0);          // 33554432 B
  unsigned short* afr = (unsigned short*)(ws + 33554432);   //  4456448 B
  unsigned short* web = (unsigned short*)(ws + 38010880);   //   131072 B
  unsigned short* wfb = (unsigned short*)(ws + 38141952);
  unsigned short* wdb = (unsigned short*)(ws + 38273024);
  unsigned int*  maxxe = (unsigned int*)(ws + 38404096);    //     8192 B
  unsigned int*  maxy  = (unsigned int*)(ws + 38412288);    //     8192 B

  unsigned short* xeT = (unsigned short*)d_out;             // scratch: 35.8 MB
  float* yout = (float*)d_out;                              // (split g2/g3 keeps
  float* hout = yout + YELEMS;                              //  aliasing race-free)

  k_pz<<<1316, 256, 0, stream>>>(We, Wf, Wd, web, wfb, wdb, xeT, (uint4*)maxxe);
  k_g1k<<<1088, 256, 0, stream>>>(A, Bp, afr, x, web, be, xeT, maxxe);
  k_conv<<<2048, 512, 0, stream>>>(xeT, afr, y1, h0);
  k_gemm2<<<1024, 256, 0, stream>>>(y1, wfb, bfc, xeT, gam, bet, y1);
  k_gemm3<<<1024, 256, 0, stream>>>(y1, wdb, bd, yout, maxy);
  k_hfin<<<8, 256, 0, stream>>>(maxxe, maxy, hout);
}

// Round 9
// 282.657 us; speedup vs baseline: 1.1429x; 1.0107x over previous
//
#include <hip/hip_runtime.h>
#include <math.h>

// ---------------------------------------------------------------------------
// RTF-SSM block, MI355X. FFT path replaced by:
//   K = impulse response of B(z)/A(z), truncated at 512 taps (Newton
//   power-series inversion, 9 wave-parallel doubling steps).
//   causal conv = Toeplitz-block bf16 MFMA (16x16x32), A-frags prebuilt.
//   GEMMs (65536x256x256) bf16 MFMA with fused bias/gelu/skip/LN/max.
// R6: VALU diet in k_conv (gelu via exp2+rcp, sliding swizzled LDS addrs).
// R9: kgen dual-G/uniform-b128 body. R10: conv 8ch x 1024t blocks.
// R13: kgen fused into gemm1 launch (kgen4, blocks [0,64)); xeT in d_out;
//   split gemm2/gemm3. 285.7us measured.
// R14: gemm2/gemm3 occupancy fix (both were ~55us at 15% occupancy, 1.2-2
//   TB/s -- latency-bound: 3 blocks/CU x 4 waves = 12 waves/CU ceiling and
//   1024-block grid = 1.33 ragged dispatch rounds):
//   512 thr / 128-t tile: 24 waves/CU (LDS 49-51K, still 3 blocks/CU),
//   grid 512 = single dispatch round (2 work-blocks/CU, 3 resident),
//   W staged once per 128t. Per-wave MFMA/epilogue code identical; only
//   mh=wv&3, nh=wv>>2 and staging bounds change.
// ---------------------------------------------------------------------------

#define BSZ   8
#define SEQ   8192
#define CHN   256
#define ORD   64
#define STAPS 512
#define NDD   17            // d-pairs: covers d = 0..33 (taps to 543 >= 511)
#define PREPAD 544          // history prepad (>= 528 needed), 16-aligned
#define XROW  (PREPAD + SEQ) // 8736 elems per (b,c) row of xe^T
#define MTOT  (BSZ * SEQ)   // 65536
#define YELEMS (MTOT * CHN) // 16777216

#define CT2   1024          // conv t-tile per block
#define CTP   1032          // conv bnc row stride (8-short pad)
#define CROW2 2048          // conv xet row elems (4 x 512 staged)

typedef short s16x8 __attribute__((ext_vector_type(8)));
typedef float f32x4 __attribute__((ext_vector_type(4)));

#define MFMA16(a, b, c) __builtin_amdgcn_mfma_f32_16x16x32_bf16((a), (b), (c), 0, 0, 0)

// async global->LDS 16B: LDS dest = wave-uniform base + lane*16
__device__ __forceinline__ void gll16(const void* g, void* l) {
  __builtin_amdgcn_global_load_lds(
      (const __attribute__((address_space(1))) unsigned int*)g,
      (__attribute__((address_space(3))) unsigned int*)l, 16, 0, 0);
}

// XOR-perm chunk layout: chunk p of (row,h) stored at elems PERMC
#define PERMC(row, h) (((row) * 8 + ((h) ^ ((row) & 7))) * 8)

__device__ __forceinline__ unsigned short f2bf(float f) {
  unsigned u = __float_as_uint(f);
  return (unsigned short)((u + 0x7FFFu + ((u >> 16) & 1u)) >> 16);
}
__device__ __forceinline__ float bf2f(unsigned short h) {
  return __uint_as_float(((unsigned)h) << 16);
}
// tanh-form gelu: x * sigmoid(2*sqrt(2/pi)*(x + 0.044715 x^3)).
// |err| vs exact erf-gelu < ~2e-4, << bf16 noise.
__device__ __forceinline__ float geluf(float x) {
  float x2 = x * x;
  float y = x * __builtin_fmaf(0.0356774081f, x2, 0.7978845608f);
  float e = __builtin_amdgcn_exp2f(-2.8853900818f * y);  // exp(-2y)
  return x * __builtin_amdgcn_rcpf(1.0f + e);
}
__device__ __forceinline__ uint4 packbf8(float4 a, float4 b) {
  uint4 r;
  r.x = (unsigned)f2bf(a.x) | ((unsigned)f2bf(a.y) << 16);
  r.y = (unsigned)f2bf(a.z) | ((unsigned)f2bf(a.w) << 16);
  r.z = (unsigned)f2bf(b.x) | ((unsigned)f2bf(b.y) << 16);
  r.w = (unsigned)f2bf(b.z) | ((unsigned)f2bf(b.w) << 16);
  return r;
}

// -------------------------------------- fused: weights->bf16 + zero prepads
__global__ __launch_bounds__(256) void k_pz(const float* we, const float* wf,
                                            const float* wd, unsigned short* owe,
                                            unsigned short* owf, unsigned short* owd,
                                            unsigned short* xeT, uint4* maxbufs) {
  int bx = blockIdx.x, tid = threadIdx.x;     // grid 1316 = 768 prep + 548 zero
  if (bx < 768) {
    int i = bx * 256 + tid;
    int which = i >> 16, off = i & 65535;
    if (which == 0)      owe[off] = f2bf(we[off]);
    else if (which == 1) owf[off] = f2bf(wf[off]);
    else                 owd[off] = f2bf(wd[off]);
  } else {
    int i = (bx - 768) * 256 + tid;
    uint4 z; z.x = 0; z.y = 0; z.z = 0; z.w = 0;
    if (i < 2048 * 68) {                      // 544 elems/row = 68 x 16B chunks
      int row = i / 68, cc = i % 68;
      *(uint4*)((char*)xeT + (size_t)row * (XROW * 2) + (size_t)cc * 16) = z;
    } else {
      int j = i - 2048 * 68;
      if (j < 1024) maxbufs[j] = z;           // maxxe (8KB) + maxy (8KB)
    }
  }
}

// ---------------- K-gen: Newton inversion of A(z), one wave per channel,
// 4 waves/block (256 thr, fused into gemm1 launch). Dual shifted G copies
// for aligned b64 per-lane reads; uniform b128 coeff reads; zero-padded
// fixed-64 loops. No barriers (per-wave private LDS slices).
__device__ __forceinline__ void kgen4(float* smemk, const float* A, const float* Bp,
                                      unsigned short* afr, int blk) {
  int tid = threadIdx.x, lane = tid & 63, wv = tid >> 6;   // wv in [0,4)
  int c = blk * 4 + wv;
  float* base = smemk + wv * 1872;            // 4 waves x 7488B = 29952B
  float* G0 = base;                           // [584], G0[64+t] = G[t]
  float* G1 = base + 584;                     // [584], G1[65+t] = G[t]
  float* Et = base + 1168;                    // [64]
  float* Asl = base + 1232;                   // [64]
  float* Bsl = base + 1296;                   // [64]
  float* Kb = base + 1360;                    // [512]

  Asl[lane] = A[(size_t)c * ORD + lane];      // a[u] = Asl[u-1], u in [1,64]
  Bsl[lane] = Bp[(size_t)c * ORD + lane];
  for (int i = lane; i < 1168; i += 64) base[i] = 0.f;  // zero both G copies
  if (lane == 0) { G0[64] = 1.f; G1[65] = 1.f; }        // G[0] = 1

  for (int n = 1; n < STAPS; n <<= 1) {
    int par = (n + lane) & 1;
    const float* Gc = par ? G1 : G0;
    int I0 = 64 + n + lane + par;             // even
    float e0 = 0.f, e1 = 0.f, e2 = 0.f, e3 = 0.f;
#pragma unroll
    for (int g = 0; g < 16; ++g) {
      float4 av = *(const float4*)&Asl[4 * g];
      float2 vA = *(const float2*)&Gc[I0 - 4 * g - 2];
      float2 vB = *(const float2*)&Gc[I0 - 4 * g - 4];
      e0 += av.x * vA.y;                      // u = 4g+1
      e1 += av.y * vA.x;                      // u = 4g+2
      e2 += av.z * vB.y;                      // u = 4g+3
      e3 += av.w * vB.x;                      // u = 4g+4
    }
    Et[lane] = (e0 + e1) + (e2 + e3);
    int nk = (n + 63) >> 6;
    for (int k = 0; k < nk; ++k) {
      int idx = k * 64 + lane;
      int parU = (idx + 1) & 1;
      const float* Gu = parU ? G1 : G0;
      int J0 = 64 + idx - 1 + parU;           // even
      float a0 = 0.f, a1 = 0.f, a2 = 0.f, a3 = 0.f;
#pragma unroll
      for (int g = 0; g < 16; ++g) {
        float4 ev = *(const float4*)&Et[4 * g];
        float2 vA = *(const float2*)&Gu[J0 - 4 * g];
        float2 vB = *(const float2*)&Gu[J0 - 4 * g - 2];
        a0 += ev.x * vA.y;                    // i = 4g
        a1 += ev.y * vA.x;                    // i = 4g+1
        a2 += ev.z * vB.y;                    // i = 4g+2
        a3 += ev.w * vB.x;                    // i = 4g+3
      }
      if (idx < n) {
        float gv = -((a0 + a1) + (a2 + a3));
        G0[64 + n + idx] = gv;
        G1[65 + n + idx] = gv;
      }
    }
  }

  for (int k = 0; k < 8; ++k) {
    int t = k * 64 + lane;
    int parB = (t + 1) & 1;
    const float* Gb = parB ? G1 : G0;
    int J0 = 64 + t - 1 + parB;               // even
    float a0 = 0.f, a1 = 0.f, a2 = 0.f, a3 = 0.f;
#pragma unroll
    for (int g = 0; g < 16; ++g) {
      float4 bv = *(const float4*)&Bsl[4 * g];
      float2 vA = *(const float2*)&Gb[J0 - 4 * g];
      float2 vB = *(const float2*)&Gb[J0 - 4 * g - 2];
      a0 += bv.x * vA.y;                      // j = 4g
      a1 += bv.y * vA.x;                      // j = 4g+1
      a2 += bv.z * vB.y;                      // j = 4g+2
      a3 += bv.w * vB.x;                      // j = 4g+3
    }
    Kb[t] = (a0 + a1) + (a2 + a3);
  }

  int m = lane & 15, quad = lane >> 4;
  for (int dd = 0; dd < NDD; ++dd) {
    unsigned short v[8];
#pragma unroll
    for (int j = 0; j < 8; ++j) {
      int k = quad * 8 + j;
      int d = 2 * dd + (k >> 4);
      int p = k & 15;
      int s = 16 * d + m - p;
      float kv = (s >= 0 && s < STAPS) ? Kb[s] : 0.f;
      v[j] = f2bf(kv);
    }
    uint4 pk;
    pk.x = (unsigned)v[0] | ((unsigned)v[1] << 16);
    pk.y = (unsigned)v[2] | ((unsigned)v[3] << 16);
    pk.z = (unsigned)v[4] | ((unsigned)v[5] << 16);
    pk.w = (unsigned)v[6] | ((unsigned)v[7] << 16);
    *(uint4*)(afr + ((size_t)(c * NDD + dd) * 64 + lane) * 8) = pk;
  }
}

// --------------- fused GEMM1 + kgen: blocks [0,64) = kgen, [64,1088) = GEMM1
// GEMM1 (transposed out): xe^T[cout][t] = W_enc x^T + b_enc
// block: 256 cout x 64 t; BK=64; W via global_load_lds, direct-store epilogue.
__global__ __launch_bounds__(256) void k_g1k(const float* A, const float* Bp,
                                             unsigned short* afr,
                                             const float* x, const unsigned short* wb,
                                             const float* benc, unsigned short* xeT,
                                             unsigned int* maxxe) {
  __shared__ __align__(16) char smem[40960];  // union: gemm1 40960B / kgen 29952B
  if (blockIdx.x < 64) {
    kgen4((float*)smem, A, Bp, afr, blockIdx.x);
    return;
  }
  unsigned short* As = (unsigned short*)smem;           // W tile, perm layout
  unsigned short* Bs = (unsigned short*)(smem + 32768); // x tile, perm layout
  int tid = threadIdx.x, lane = tid & 63, wv = tid >> 6;
  int ln15 = lane & 15, hf = lane >> 4;
  size_t t0 = (size_t)(blockIdx.x - 64) * 64; // 1024 gemm blocks
  int b = (int)(t0 >> 13), tin = (int)(t0 & 8191);
  f32x4 acc[4][4];
#pragma unroll
  for (int i = 0; i < 4; ++i)
#pragma unroll
    for (int j = 0; j < 4; ++j) { acc[i][j][0]=0.f; acc[i][j][1]=0.f; acc[i][j][2]=0.f; acc[i][j][3]=0.f; }

  for (int k0 = 0; k0 < CHN; k0 += 64) {
    __syncthreads();
#pragma unroll
    for (int i = 0; i < 8; ++i) {
      int p = 512 * wv + 64 * i + lane;
      int row = p >> 3, h = (p & 7) ^ (row & 7);
      gll16(wb + (size_t)row * CHN + k0 + h * 8, &As[(512 * wv + 64 * i) * 8]);
    }
    {  // x: 64x64 fp32->bf16, 2 chunks/thread
      int row = tid >> 2, hb = (tid & 3) * 2;
      const float* src = x + (t0 + row) * CHN + k0 + hb * 8;
      float4 f0 = *(const float4*)src;
      float4 f1 = *(const float4*)(src + 4);
      float4 f2 = *(const float4*)(src + 8);
      float4 f3 = *(const float4*)(src + 12);
      *(uint4*)&Bs[PERMC(row, hb)]     = packbf8(f0, f1);
      *(uint4*)&Bs[PERMC(row, hb + 1)] = packbf8(f2, f3);
    }
    __syncthreads();
#pragma unroll
    for (int ks = 0; ks < 2; ++ks) {
      s16x8 af[4], bfr[4];
#pragma unroll
      for (int mt = 0; mt < 4; ++mt) {
        int row = 64 * wv + 16 * mt + ln15;
        af[mt] = *(const s16x8*)&As[PERMC(row, ks * 4 + hf)];
      }
#pragma unroll
      for (int nt = 0; nt < 4; ++nt) {
        int row = 16 * nt + ln15;
        bfr[nt] = *(const s16x8*)&Bs[PERMC(row, ks * 4 + hf)];
      }
#pragma unroll
      for (int mt = 0; mt < 4; ++mt)
#pragma unroll
        for (int nt = 0; nt < 4; ++nt)
          acc[mt][nt] = MFMA16(af[mt], bfr[nt], acc[mt][nt]);
    }
  }
  // epilogue: D[m=cout][n=t]; col=lane&15=t, row=quad*4+r
  int quad = hf;
#pragma unroll
  for (int mt = 0; mt < 4; ++mt) {
#pragma unroll
    for (int r = 0; r < 4; ++r) {
      int row = 64 * wv + 16 * mt + 4 * quad + r;
      float bias = benc[row];
      float mv = 0.f;
#pragma unroll
      for (int nt = 0; nt < 4; ++nt) {
        float v = acc[mt][nt][r] + bias;
        int t = tin + 16 * nt + ln15;
        xeT[(size_t)(b * CHN + row) * XROW + PREPAD + t] = f2bf(v);
        mv = fmaxf(mv, fabsf(v));
      }
      mv = fmaxf(mv, __shfl_xor(mv, 1)); mv = fmaxf(mv, __shfl_xor(mv, 2));
      mv = fmaxf(mv, __shfl_xor(mv, 4)); mv = fmaxf(mv, __shfl_xor(mv, 8));
      if (ln15 == 0) atomicMax(&maxxe[b * CHN + row], __float_as_uint(mv));
    }
  }
}

// ------------- conv: y1[t][c] = gelu(FIR(xe) + h0*xe)
// block = 8 ch x 1024 t (512 thr, 8 waves, wave owns 1 channel);
// A-frags in VGPRs; swizzled LDS addrs slide (rotate-8 + (a+512)^64).
__global__ __launch_bounds__(512) void k_conv(const unsigned short* xeT,
                                              const unsigned short* afr,
                                              unsigned short* y1, const float* h0p) {
  __shared__ __align__(16) unsigned short xet[8 * CROW2]; // 32KB
  __shared__ __align__(16) unsigned short bnc[8 * CTP];   // 16.5KB
  int tid = threadIdx.x, lane = tid & 63, wv = tid >> 6;
  int idx = blockIdx.x;                          // grid 2048 = 8b x 32cg x 8tg
  int tg = idx & 7, cg = (idx >> 3) & 31, b = idx >> 8;
  int c0 = cg * 8, t0 = tg * CT2;
  int c = c0 + wv;

  s16x8 afrg[NDD];
  {
    const unsigned short* ap = afr + (size_t)c * (NDD * 512) + (size_t)lane * 8;
#pragma unroll
    for (int dd = 0; dd < NDD; ++dd)
      afrg[dd] = *(const s16x8*)(ap + (size_t)dd * 512);
  }
  {
    int lp = lane ^ ((lane >> 3) & 7);
    const unsigned short* gbase = xeT + (size_t)(b * CHN + c) * XROW + t0;
    unsigned short* lbase = &xet[wv * CROW2];
#pragma unroll
    for (int k = 0; k < 4; ++k)
      gll16(gbase + (size_t)(64 * k + lp) * 8, &lbase[k * 64 * 8]);
  }
  float h0 = h0p[0];

  int n = lane & 15, quad = lane >> 4;
  int qc = quad - ((quad >> 1) << 2);            // 0,1,-2,-1
  const char* xb = (const char*)&xet[wv * CROW2];

  int ad[NDD];
  {
    int cb0 = 2 * n + qc + 68;
#pragma unroll
    for (int dd = 0; dd < NDD; ++dd) {
      int cc = cb0 - 4 * dd;
      ad[dd] = (cc ^ ((cc >> 3) & 7)) * 16;
    }
  }
  int ead;
  {
    int ch = 68 + 2 * n + (quad >> 1);
    ead = (ch ^ ((ch >> 3) & 7)) * 16 + 8 * (quad & 1);
  }
  __syncthreads();

#pragma unroll 1
  for (int s = 0; s < 4; ++s) {
    f32x4 a0, a1;
    a0[0]=0.f; a0[1]=0.f; a0[2]=0.f; a0[3]=0.f;
    a1[0]=0.f; a1[1]=0.f; a1[2]=0.f; a1[3]=0.f;
#pragma unroll
    for (int dd = 0; dd < 16; dd += 2) {
      a0 = MFMA16(afrg[dd],     *(const s16x8*)(xb + ad[dd]),     a0);
      a1 = MFMA16(afrg[dd + 1], *(const s16x8*)(xb + ad[dd + 1]), a1);
    }
    a0 = MFMA16(afrg[16], *(const s16x8*)(xb + ad[16]), a0);
    uint2 xvp = *(const uint2*)(xb + ead);
    unsigned short o[4];
#pragma unroll
    for (int r = 0; r < 4; ++r) {
      float xv = bf2f(((const unsigned short*)&xvp)[r]);
      float v = (a0[r] + a1[r]) + h0 * xv;
      o[r] = f2bf(geluf(v));
    }
    uint2 pw;
    pw.x = (unsigned)o[0] | ((unsigned)o[1] << 16);
    pw.y = (unsigned)o[2] | ((unsigned)o[3] << 16);
    *(uint2*)&bnc[wv * CTP + 256 * s + 16 * n + 4 * quad] = pw;
#pragma unroll
    for (int dd = 16; dd >= 8; --dd) ad[dd] = ad[dd - 8];
#pragma unroll
    for (int dd = 0; dd < 8; ++dd) ad[dd] = (ad[dd] + 512) ^ 64;
    ead = (ead + 512) ^ 64;
  }
  __syncthreads();
  {
    const size_t obase = (size_t)(b * SEQ + t0) * CHN + c0;
    int tb = tid >> 1, h = (tid & 1) * 4;
#pragma unroll
    for (int s = 0; s < 4; ++s) {
      int tl = 256 * s + tb;
      uint2 pk;
      pk.x = (unsigned)bnc[(h + 0) * CTP + tl] | ((unsigned)bnc[(h + 1) * CTP + tl] << 16);
      pk.y = (unsigned)bnc[(h + 2) * CTP + tl] | ((unsigned)bnc[(h + 3) * CTP + tl] << 16);
      *(uint2*)(y1 + obase + (size_t)tl * CHN + h) = pk;
    }
  }
}

// ------ GEMM2: y2n = LN(gelu(y1 W_fc^T + b_fc) + xe)*gamma+beta, in-place y1
// R14: 512 thr / 128-t tile; 8 waves (mh=wv&3 m-slice, nh=wv>>2 cout-half);
// grid 512 = single dispatch round, 24 waves/CU (LDS 51200B, 3 blocks/CU).
__global__ __launch_bounds__(512) void k_gemm2(const unsigned short* y1,
                                               const unsigned short* wb, const float* bfc,
                                               const unsigned short* xeT, const float* gam,
                                               const float* bet, unsigned short* y2n) {
  __shared__ __align__(16) unsigned short Ws[256 * 64];   // 32768B
  __shared__ __align__(16) unsigned short Asb[128 * 64];  // 16384B
  __shared__ float pl[128][2][2];                         //  2048B
  int tid = threadIdx.x, lane = tid & 63, wv = tid >> 6;
  int ln15 = lane & 15, hf = lane >> 4, quad = hf;
  size_t M0 = (size_t)blockIdx.x * 128;          // grid 512
  int b = (int)(M0 >> 13), tin = (int)(M0 & 8191);
  int mh = wv & 3, nh = wv >> 2;
  f32x4 acc[2][8];
#pragma unroll
  for (int i = 0; i < 2; ++i)
#pragma unroll
    for (int j = 0; j < 8; ++j) { acc[i][j][0]=0.f; acc[i][j][1]=0.f; acc[i][j][2]=0.f; acc[i][j][3]=0.f; }

  for (int k0 = 0; k0 < CHN; k0 += 64) {
    __syncthreads();
#pragma unroll
    for (int i = 0; i < 4; ++i) {               // W: 2048 chunks / 512 thr
      int p = 256 * wv + 64 * i + lane;
      int row = p >> 3, h = (p & 7) ^ (row & 7);
      gll16(wb + (size_t)row * CHN + k0 + h * 8, &Ws[(256 * wv + 64 * i) * 8]);
    }
#pragma unroll
    for (int i = 0; i < 2; ++i) {               // A: 1024 chunks (128 rows)
      int p = 128 * wv + 64 * i + lane;
      int row = p >> 3, h = (p & 7) ^ (row & 7);
      gll16(y1 + (M0 + row) * CHN + k0 + h * 8, &Asb[(128 * wv + 64 * i) * 8]);
    }
    __syncthreads();
#pragma unroll
    for (int ks = 0; ks < 2; ++ks) {
      s16x8 af[2], bfr[8];
#pragma unroll
      for (int mt = 0; mt < 2; ++mt) {
        int row = 32 * mh + 16 * mt + ln15;
        af[mt] = *(const s16x8*)&Asb[PERMC(row, ks * 4 + hf)];
      }
#pragma unroll
      for (int nt = 0; nt < 8; ++nt) {
        int row = 128 * nh + 16 * nt + ln15;
        bfr[nt] = *(const s16x8*)&Ws[PERMC(row, ks * 4 + hf)];
      }
#pragma unroll
      for (int mt = 0; mt < 2; ++mt)
#pragma unroll
        for (int nt = 0; nt < 8; ++nt)
          acc[mt][nt] = MFMA16(af[mt], bfr[nt], acc[mt][nt]);
    }
  }
  float g8[8], be8[8], bf8[8];
#pragma unroll
  for (int nt = 0; nt < 8; ++nt) {
    int col = 128 * nh + 16 * nt + ln15;
    g8[nt] = gam[col]; be8[nt] = bet[col]; bf8[nt] = bfc[col];
  }
#pragma unroll
  for (int mt = 0; mt < 2; ++mt) {
    int mlb = 32 * mh + 16 * mt + 4 * quad;
    uint2 xv2[8];
#pragma unroll
    for (int nt = 0; nt < 8; ++nt) {            // xe skip: 4 consecutive t per lane
      int col = 128 * nh + 16 * nt + ln15;
      xv2[nt] = *(const uint2*)(xeT + (size_t)(b * CHN + col) * XROW + PREPAD + tin + mlb);
    }
#pragma unroll
    for (int r = 0; r < 4; ++r) {
      int ml = mlb + r;
      float s1 = 0.f, s2 = 0.f;
#pragma unroll
      for (int nt = 0; nt < 8; ++nt) {
        float t2 = acc[mt][nt][r] + bf8[nt];
        float xv = bf2f(((const unsigned short*)&xv2[nt])[r]);
        float y2 = geluf(t2) + xv;
        acc[mt][nt][r] = y2;
        s1 += y2; s2 += y2 * y2;
      }
      s1 += __shfl_xor(s1, 1); s2 += __shfl_xor(s2, 1);
      s1 += __shfl_xor(s1, 2); s2 += __shfl_xor(s2, 2);
      s1 += __shfl_xor(s1, 4); s2 += __shfl_xor(s2, 4);
      s1 += __shfl_xor(s1, 8); s2 += __shfl_xor(s2, 8);
      if (ln15 == 0) { pl[ml][nh][0] = s1; pl[ml][nh][1] = s2; }
    }
  }
  __syncthreads();
#pragma unroll
  for (int mt = 0; mt < 2; ++mt) {
#pragma unroll
    for (int r = 0; r < 4; ++r) {
      int ml = 32 * mh + 16 * mt + 4 * quad + r;
      float s1 = pl[ml][0][0] + pl[ml][1][0];
      float s2 = pl[ml][0][1] + pl[ml][1][1];
      float mu = s1 * (1.f / 256.f);
      float var = s2 * (1.f / 256.f) - mu * mu;
      float ri = rsqrtf(var + 1e-5f);
#pragma unroll
      for (int nt = 0; nt < 8; ++nt) {
        int col = 128 * nh + 16 * nt + ln15;
        float yn = (acc[mt][nt][r] - mu) * ri * g8[nt] + be8[nt];
        y2n[(M0 + ml) * CHN + col] = f2bf(yn);
      }
    }
  }
}

// ------------------- GEMM3: y = y2n W_dec^T + b_dec (fp32 out) + maxy atomics
// R14: 512 thr / 128-t tile (same restructure as gemm2).
__global__ __launch_bounds__(512) void k_gemm3(const unsigned short* y2n,
                                               const unsigned short* wb, const float* bd,
                                               float* yout, unsigned int* maxy) {
  __shared__ __align__(16) unsigned short Ws[256 * 64];   // 32768B
  __shared__ __align__(16) unsigned short Asb[128 * 64];  // 16384B
  int tid = threadIdx.x, lane = tid & 63, wv = tid >> 6;
  int ln15 = lane & 15, hf = lane >> 4, quad = hf;
  size_t M0 = (size_t)blockIdx.x * 128;          // grid 512
  int b = (int)(M0 >> 13);
  int mh = wv & 3, nh = wv >> 2;
  f32x4 acc[2][8];
#pragma unroll
  for (int i = 0; i < 2; ++i)
#pragma unroll
    for (int j = 0; j < 8; ++j) { acc[i][j][0]=0.f; acc[i][j][1]=0.f; acc[i][j][2]=0.f; acc[i][j][3]=0.f; }

  for (int k0 = 0; k0 < CHN; k0 += 64) {
    __syncthreads();
#pragma unroll
    for (int i = 0; i < 4; ++i) {               // W: 2048 chunks / 512 thr
      int p = 256 * wv + 64 * i + lane;
      int row = p >> 3, h = (p & 7) ^ (row & 7);
      gll16(wb + (size_t)row * CHN + k0 + h * 8, &Ws[(256 * wv + 64 * i) * 8]);
    }
#pragma unroll
    for (int i = 0; i < 2; ++i) {               // A: 1024 chunks (128 rows)
      int p = 128 * wv + 64 * i + lane;
      int row = p >> 3, h = (p & 7) ^ (row & 7);
      gll16(y2n + (M0 + row) * CHN + k0 + h * 8, &Asb[(128 * wv + 64 * i) * 8]);
    }
    __syncthreads();
#pragma unroll
    for (int ks = 0; ks < 2; ++ks) {
      s16x8 af[2], bfr[8];
#pragma unroll
      for (int mt = 0; mt < 2; ++mt) {
        int row = 32 * mh + 16 * mt + ln15;
        af[mt] = *(const s16x8*)&Asb[PERMC(row, ks * 4 + hf)];
      }
#pragma unroll
      for (int nt = 0; nt < 8; ++nt) {
        int row = 128 * nh + 16 * nt + ln15;
        bfr[nt] = *(const s16x8*)&Ws[PERMC(row, ks * 4 + hf)];
      }
#pragma unroll
      for (int mt = 0; mt < 2; ++mt)
#pragma unroll
        for (int nt = 0; nt < 8; ++nt)
          acc[mt][nt] = MFMA16(af[mt], bfr[nt], acc[mt][nt]);
    }
  }
  float bd8[8];
#pragma unroll
  for (int nt = 0; nt < 8; ++nt) bd8[nt] = bd[128 * nh + 16 * nt + ln15];
#pragma unroll
  for (int mt = 0; mt < 2; ++mt)
#pragma unroll
    for (int r = 0; r < 4; ++r) {
      int ml = 32 * mh + 16 * mt + 4 * quad + r;
#pragma unroll
      for (int nt = 0; nt < 8; ++nt) {
        int col = 128 * nh + 16 * nt + ln15;
        float v = acc[mt][nt][r] + bd8[nt];
        acc[mt][nt][r] = v;
        yout[(M0 + ml) * CHN + col] = v;
      }
    }
#pragma unroll
  for (int nt = 0; nt < 8; ++nt) {
    int col = 128 * nh + 16 * nt + ln15;
    float mv = 0.f;
#pragma unroll
    for (int mt = 0; mt < 2; ++mt)
#pragma unroll
      for (int r = 0; r < 4; ++r) mv = fmaxf(mv, fabsf(acc[mt][nt][r]));
    mv = fmaxf(mv, __shfl_xor(mv, 16));
    mv = fmaxf(mv, __shfl_xor(mv, 32));
    if (quad == 0) atomicMax(&maxy[b * CHN + col], __float_as_uint(mv));
  }
}

// ------------------------------------------------------------ h = my/(mx+eps)
__global__ __launch_bounds__(256) void k_hfin(const unsigned int* maxxe,
                                              const unsigned int* maxy, float* hout) {
  int i = blockIdx.x * 256 + threadIdx.x;        // grid 8
  if (i < BSZ * CHN) {
    float mx = __uint_as_float(maxxe[i]);
    float my = __uint_as_float(maxy[i]);
    hout[i] = my / (mx + 1e-6f);
  }
}

// ---------------------------------------------------------------------------
extern "C" void kernel_launch(void* const* d_in, const int* in_sizes, int n_in,
                              void* d_out, int out_size, void* d_ws, size_t ws_size,
                              hipStream_t stream) {
  const float* x   = (const float*)d_in[0];
  const float* A   = (const float*)d_in[1];
  const float* Bp  = (const float*)d_in[2];
  const float* h0  = (const float*)d_in[3];
  const float* We  = (const float*)d_in[4];
  const float* be  = (const float*)d_in[5];
  const float* Wf  = (const float*)d_in[6];
  const float* bfc = (const float*)d_in[7];
  const float* gam = (const float*)d_in[8];
  const float* bet = (const float*)d_in[9];
  const float* Wd  = (const float*)d_in[10];
  const float* bd  = (const float*)d_in[11];

  char* ws = (char*)d_ws;
  unsigned short* y1  = (unsigned short*)(ws + 0);          // 33554432 B
  unsigned short* afr = (unsigned short*)(ws + 33554432);   //  4456448 B
  unsigned short* web = (unsigned short*)(ws + 38010880);   //   131072 B
  unsigned short* wfb = (unsigned short*)(ws + 38141952);
  unsigned short* wdb = (unsigned short*)(ws + 38273024);
  unsigned int*  maxxe = (unsigned int*)(ws + 38404096);    //     8192 B
  unsigned int*  maxy  = (unsigned int*)(ws + 38412288);    //     8192 B

  unsigned short* xeT = (unsigned short*)d_out;             // scratch: 35.8 MB
  float* yout = (float*)d_out;                              // (split g2/g3 keeps
  float* hout = yout + YELEMS;                              //  aliasing race-free)

  k_pz<<<1316, 256, 0, stream>>>(We, Wf, Wd, web, wfb, wdb, xeT, (uint4*)maxxe);
  k_g1k<<<1088, 256, 0, stream>>>(A, Bp, afr, x, web, be, xeT, maxxe);
  k_conv<<<2048, 512, 0, stream>>>(xeT, afr, y1, h0);
  k_gemm2<<<512, 512, 0, stream>>>(y1, wfb, bfc, xeT, gam, bet, y1);
  k_gemm3<<<512, 512, 0, stream>>>(y1, wdb, bd, yout, maxy);
  k_hfin<<<8, 256, 0, stream>>>(maxxe, maxy, hout);
}